// Round 2
// baseline (1629.497 us; speedup 1.0000x reference)
//
#include <hip/hip_runtime.h>

typedef unsigned short u16;
typedef unsigned int   u32;
typedef __attribute__((ext_vector_type(4))) u16   u16x4;
typedef __attribute__((ext_vector_type(8))) u16   u16x8;
typedef __attribute__((ext_vector_type(8))) __bf16 bf16x8;
typedef __attribute__((ext_vector_type(4))) float f32x4;

#define DEV static __device__ __forceinline__

constexpr int DIM = 512, NHEAD = 8, DHEAD = 64, DFFN = 2048, NLAY = 6, SEQ = 512, BATCH = 8;
constexpr int MROWS = BATCH * SEQ;            // 4096 token rows
constexpr long HD = (long)SEQ * DHEAD;        // 32768 per-head q/k/v block
constexpr long SS = (long)SEQ * SEQ;          // 262144 per-head score block

DEV float bf2f(u16 u) { union { u32 i; float f; } x; x.i = (u32)u << 16; return x.f; }
DEV u16 f2bf(float f) { union { float f; u32 i; } x; x.f = f; u32 r = x.i + 0x7fffu + ((x.i >> 16) & 1u); return (u16)(r >> 16); }

DEV void gl_lds16(const u16* g, u16* l) {
    __builtin_amdgcn_global_load_lds((const __attribute__((address_space(1))) u32*)(const void*)g,
                                     (__attribute__((address_space(3))) u32*)(void*)l, 16, 0, 0);
}

// ---------------------------------------------------------------------------
// Weight transpose + f32->bf16:  out[z*outLS + n*K + k] = bf16(in[z*K*N + k*N + n])
// ---------------------------------------------------------------------------
__global__ __launch_bounds__(256) void transpose_w(const float* __restrict__ in, u16* __restrict__ out,
                                                   int K, int N, long outLS)
{
    __shared__ u16 t[32][33];
    long bi = (long)blockIdx.z * K * N, bo = (long)blockIdx.z * outLS;
    int k0 = blockIdx.y * 32, n0 = blockIdx.x * 32;
    int tx = threadIdx.x & 31, ty = threadIdx.x >> 5;
    #pragma unroll
    for (int i = ty; i < 32; i += 8) t[i][tx] = f2bf(in[bi + (long)(k0 + i) * N + n0 + tx]);
    __syncthreads();
    #pragma unroll
    for (int i = ty; i < 32; i += 8) out[bo + (long)(n0 + i) * K + k0 + tx] = t[tx][i];
}

// concat per-layer bias vectors (each NLAY x 512) into [NLAY][nsrc*512]
__global__ __launch_bounds__(256) void concat_bias(const float* __restrict__ a, const float* __restrict__ b,
                                                   const float* __restrict__ c, float* __restrict__ out, int nsrc)
{
    int i = blockIdx.x * 256 + threadIdx.x;
    int col = i & 511, j = (i >> 9) % nsrc, l = i / (nsrc * 512);
    const float* s = (j == 0) ? a : (j == 1) ? b : c;
    out[i] = s[l * 512 + col];
}

__global__ __launch_bounds__(256) void conv_f32_bf16(const float* __restrict__ in, u16* __restrict__ out)
{
    long i = ((long)blockIdx.x * 256 + threadIdx.x) * 4;
    float4 v = *(const float4*)(in + i);
    u16x4 o; o.x = f2bf(v.x); o.y = f2bf(v.y); o.z = f2bf(v.z); o.w = f2bf(v.w);
    *(u16x4*)(out + i) = o;
}

// ---------------------------------------------------------------------------
// Embedding * sqrt(D) + sinusoidal positional encoding -> x (f32) and xb (bf16)
// ---------------------------------------------------------------------------
__global__ __launch_bounds__(256) void embed_pe(const int* __restrict__ targets, const float* __restrict__ emb,
                                                float* __restrict__ x, u16* __restrict__ xb)
{
    int t4 = (blockIdx.x * 256 + threadIdx.x) * 4;
    int d = t4 & (DIM - 1);
    int s = (t4 >> 9) & (SEQ - 1);
    int b = t4 >> 18;
    int tok = targets[s * BATCH + b];
    float4 e = *(const float4*)(emb + (long)tok * DIM + d);
    float o[4]; u16x4 ob;
    const float ef[4] = { e.x, e.y, e.z, e.w };
    #pragma unroll
    for (int j = 0; j < 4; ++j) {
        int dd = d + j;
        float div = expf((float)(dd & ~1) * -0.017988946039016f);  // -ln(10000)/512
        float ang = (float)s * div;
        float pe = (dd & 1) ? cosf(ang) : sinf(ang);
        float val = ef[j] * 22.627416997969522f + pe;              // sqrt(512)
        o[j] = val; ob[j] = f2bf(val);
    }
    long idx = ((long)b * SEQ + s) * DIM + d;
    *(float4*)(x + idx) = *(const float4*)o;
    *(u16x4*)(xb + idx) = ob;
}

// scatter helpers: (B*S, D)-indexed value -> head-split layouts
DEV void scat_sd(u16* dst, int mm, int col, float v) {   // (B,NH,S,DH)
    dst[(long)((mm >> 9) * NHEAD + (col >> 6)) * HD + (long)(mm & 511) * DHEAD + (col & 63)] = f2bf(v);
}
DEV void scat_ds(u16* dst, int mm, int col, float v) {   // (B,NH,DH,S)
    dst[(long)((mm >> 9) * NHEAD + (col >> 6)) * HD + (long)(col & 63) * SEQ + (mm & 511)] = f2bf(v);
}

// ---------------------------------------------------------------------------
// m97-structure GEMM: C = A @ Bt^T + bias. A: Mx K bf16, Bt: NxK bf16.
// BM=128, BK=32, 4 waves, global_load_lds width-16 into linear LDS,
// double-buffered, one barrier per K-step.
// EPI: 0=f32 (ldc), 1=bf16+relu (ldc), 2=Q scatter, 3=KV scatter, 4=QKV scatter
// ---------------------------------------------------------------------------
template <int BN, int EPI>
__global__ __launch_bounds__(256) void gemm_glds(const u16* __restrict__ A, const u16* __restrict__ Bt,
                                                 void* __restrict__ C0, void* __restrict__ C1, void* __restrict__ C2,
                                                 const float* __restrict__ bias, int K, int ldc)
{
    constexpr int NCHA = 8;              // A chunks of 16 rows (128 rows)
    constexpr int NCHB = BN / 16;        // B chunks
    constexpr int NCH  = NCHA + NCHB;
    constexpr int LDSE = 4096 + BN * 32; // elements per buffer (A then B)
    constexpr int NI   = BN / 32;        // N fragments per wave
    __shared__ __align__(16) u16 lds[2][LDSE];

    const int tid = threadIdx.x, lane = tid & 63, wid = tid >> 6;
    const int m0 = blockIdx.y * 128, n0 = blockIdx.x * BN;
    const int wr = (wid >> 1) * 64, wc = (wid & 1) * (BN / 2);
    const int fr = lane & 15, fq = lane >> 4, kg = fq * 8;
    const int srow = lane >> 2, scol = (lane & 3) * 8;   // staging lane map

    f32x4 acc[4][NI] = {};

    auto stage = [&](int buf, int k0) {
        for (int c = wid; c < NCH; c += 4) {
            if (c < NCHA) {
                gl_lds16(A + (long)(m0 + c * 16 + srow) * K + k0 + scol, &lds[buf][c * 512]);
            } else {
                gl_lds16(Bt + (long)(n0 + (c - NCHA) * 16 + srow) * K + k0 + scol,
                         &lds[buf][4096 + (c - NCHA) * 512]);
            }
        }
    };

    const int nt = K >> 5;
    stage(0, 0);
    __syncthreads();                        // drains vmcnt(0): buf0 ready
    int cur = 0;
    for (int t = 0; t < nt; ++t) {
        if (t + 1 < nt) stage(cur ^ 1, (t + 1) << 5);
        bf16x8 af[4], bfv[NI];
        #pragma unroll
        for (int mi = 0; mi < 4; ++mi)
            af[mi] = *(const bf16x8*)&lds[cur][(wr + mi * 16 + fr) * 32 + kg];
        #pragma unroll
        for (int ni = 0; ni < NI; ++ni)
            bfv[ni] = *(const bf16x8*)&lds[cur][4096 + (wc + ni * 16 + fr) * 32 + kg];
        #pragma unroll
        for (int mi = 0; mi < 4; ++mi)
            #pragma unroll
            for (int ni = 0; ni < NI; ++ni)
                acc[mi][ni] = __builtin_amdgcn_mfma_f32_16x16x32_bf16(af[mi], bfv[ni], acc[mi][ni], 0, 0, 0);
        __syncthreads();                    // drains prefetch vmcnt + lgkm, then barrier
        cur ^= 1;
    }

    #pragma unroll
    for (int mi = 0; mi < 4; ++mi)
    #pragma unroll
    for (int ni = 0; ni < NI; ++ni)
    #pragma unroll
    for (int rr = 0; rr < 4; ++rr) {
        int mm = m0 + wr + mi * 16 + fq * 4 + rr;
        int nn = n0 + wc + ni * 16 + fr;
        float v = acc[mi][ni][rr] + bias[nn];
        if (EPI == 0) {
            ((float*)C0)[(long)mm * ldc + nn] = v;
        } else if (EPI == 1) {
            ((u16*)C0)[(long)mm * ldc + nn] = f2bf(fmaxf(v, 0.f));
        } else if (EPI == 2) {
            scat_sd((u16*)C0, mm, nn, v);
        } else if (EPI == 3) {
            if (nn < 512) scat_sd((u16*)C1, mm, nn, v);
            else          scat_ds((u16*)C2, mm, nn - 512, v);
        } else {            // QKV
            int which = nn >> 9, col = nn & 511;
            if (which == 0)      scat_sd((u16*)C0, mm, col, v);
            else if (which == 1) scat_sd((u16*)C1, mm, col, v);
            else                 scat_ds((u16*)C2, mm, col, v);
        }
    }
}

// ---------------------------------------------------------------------------
// Batched 64x64-tile GEMM for attention scores / PV (kept from R1).
// EPI: 1 = bf16 plain. C batch offset: (z/cDiv)*cOut + (z%cDiv)*cIn.
// ---------------------------------------------------------------------------
template <int EPI, bool RELU, bool BIAS>
__global__ __launch_bounds__(256) void gemm_bt(const u16* __restrict__ A, const u16* __restrict__ Bt,
                                               void* __restrict__ C, const float* __restrict__ bias,
                                               int M, int N, int K,
                                               long aB, long bB, long cOut, long cIn, int cDiv, int ldc)
{
    __shared__ __align__(16) u16 As[64][40];
    __shared__ __align__(16) u16 Bs[64][40];
    const int tid = threadIdx.x, lane = tid & 63, wid = tid >> 6;
    const int m0 = blockIdx.y * 64, n0 = blockIdx.x * 64, z = blockIdx.z;
    const u16* Ab = A + (long)z * aB;
    const u16* Bb = Bt + (long)z * bB;
    const int r  = tid >> 2, c4 = (tid & 3) * 8;
    const int wr = (wid >> 1) * 32, wc = (wid & 1) * 32;
    const int fr = lane & 15, kg = (lane >> 4) * 8, fq = lane >> 4;

    f32x4 acc[2][2] = {};
    u16x8 av = *(const u16x8*)(Ab + (long)(m0 + r) * K + c4);
    u16x8 bv = *(const u16x8*)(Bb + (long)(n0 + r) * K + c4);

    for (int k0 = 0; k0 < K; k0 += 32) {
        __syncthreads();
        *(u16x8*)&As[r][c4] = av;
        *(u16x8*)&Bs[r][c4] = bv;
        if (k0 + 32 < K) {
            av = *(const u16x8*)(Ab + (long)(m0 + r) * K + (k0 + 32) + c4);
            bv = *(const u16x8*)(Bb + (long)(n0 + r) * K + (k0 + 32) + c4);
        }
        __syncthreads();
        bf16x8 a0 = *(const bf16x8*)&As[wr + fr][kg];
        bf16x8 a1 = *(const bf16x8*)&As[wr + 16 + fr][kg];
        bf16x8 b0 = *(const bf16x8*)&Bs[wc + fr][kg];
        bf16x8 b1 = *(const bf16x8*)&Bs[wc + 16 + fr][kg];
        acc[0][0] = __builtin_amdgcn_mfma_f32_16x16x32_bf16(a0, b0, acc[0][0], 0, 0, 0);
        acc[0][1] = __builtin_amdgcn_mfma_f32_16x16x32_bf16(a0, b1, acc[0][1], 0, 0, 0);
        acc[1][0] = __builtin_amdgcn_mfma_f32_16x16x32_bf16(a1, b0, acc[1][0], 0, 0, 0);
        acc[1][1] = __builtin_amdgcn_mfma_f32_16x16x32_bf16(a1, b1, acc[1][1], 0, 0, 0);
    }

    const long cb = (long)(z / cDiv) * cOut + (long)(z % cDiv) * cIn;
    #pragma unroll
    for (int mi = 0; mi < 2; ++mi)
    #pragma unroll
    for (int ni = 0; ni < 2; ++ni)
    #pragma unroll
    for (int rr = 0; rr < 4; ++rr) {
        int mm = m0 + wr + mi * 16 + fq * 4 + rr;
        int nn = n0 + wc + ni * 16 + fr;
        float v = acc[mi][ni][rr];
        if (BIAS) v += bias[nn];
        if (RELU) v = fmaxf(v, 0.f);
        ((u16*)C)[cb + (long)mm * ldc + nn] = f2bf(v);
    }
}

// ---------------------------------------------------------------------------
// Row softmax over bf16 scores (in-place), scale 1/8, optional causal mask.
// ---------------------------------------------------------------------------
__global__ __launch_bounds__(256) void softmax_rows(u16* __restrict__ att, int causal)
{
    int row = blockIdx.x * 4 + (threadIdx.x >> 6);
    int lane = threadIdx.x & 63;
    int q = row & (SEQ - 1);
    u16* p = att + (long)row * SEQ + lane * 8;
    u16x8 v = *(u16x8*)p;
    float f[8], mx = -3.0e38f;
    #pragma unroll
    for (int j = 0; j < 8; ++j) {
        int col = lane * 8 + j;
        float s = bf2f(v[j]) * 0.125f;               // 1/sqrt(64)
        if (causal && col > q) s = -3.0e38f;
        f[j] = s; mx = fmaxf(mx, s);
    }
    #pragma unroll
    for (int o = 32; o; o >>= 1) mx = fmaxf(mx, __shfl_xor(mx, o, 64));
    float sum = 0.f;
    #pragma unroll
    for (int j = 0; j < 8; ++j) { f[j] = __expf(f[j] - mx); sum += f[j]; }
    #pragma unroll
    for (int o = 32; o; o >>= 1) sum += __shfl_xor(sum, o, 64);
    float inv = 1.0f / sum;
    u16x8 ov;
    #pragma unroll
    for (int j = 0; j < 8; ++j) ov[j] = f2bf(f[j] * inv);
    *(u16x8*)p = ov;
}

// ---------------------------------------------------------------------------
// x = LayerNorm(x + y) * g + be;  writes f32 (xo) and bf16 (xb).
// ---------------------------------------------------------------------------
__global__ __launch_bounds__(256) void add_ln(const float* x, const float* __restrict__ y,
                                              float* xo, u16* __restrict__ xb,
                                              const float* __restrict__ g, const float* __restrict__ be)
{
    int row = blockIdx.x * 4 + (threadIdx.x >> 6);
    int lane = threadIdx.x & 63;
    long off = (long)row * DIM + lane * 8;
    float v[8];
    {
        float4 a0 = *(const float4*)(x + off);
        float4 a1 = *(const float4*)(x + off + 4);
        float4 b0 = *(const float4*)(y + off);
        float4 b1 = *(const float4*)(y + off + 4);
        v[0] = a0.x + b0.x; v[1] = a0.y + b0.y; v[2] = a0.z + b0.z; v[3] = a0.w + b0.w;
        v[4] = a1.x + b1.x; v[5] = a1.y + b1.y; v[6] = a1.z + b1.z; v[7] = a1.w + b1.w;
    }
    float sum = 0.f;
    #pragma unroll
    for (int j = 0; j < 8; ++j) sum += v[j];
    #pragma unroll
    for (int o = 32; o; o >>= 1) sum += __shfl_xor(sum, o, 64);
    float mean = sum * (1.0f / DIM);
    float vs = 0.f;
    #pragma unroll
    for (int j = 0; j < 8; ++j) { float d = v[j] - mean; vs += d * d; }
    #pragma unroll
    for (int o = 32; o; o >>= 1) vs += __shfl_xor(vs, o, 64);
    float rstd = rsqrtf(vs * (1.0f / DIM) + 1e-5f);
    float outv[8]; u16x8 ob;
    #pragma unroll
    for (int j = 0; j < 8; ++j) {
        int col = lane * 8 + j;
        float r = (v[j] - mean) * rstd * g[col] + be[col];
        outv[j] = r; ob[j] = f2bf(r);
    }
    *(float4*)(xo + off)     = *(const float4*)&outv[0];
    *(float4*)(xo + off + 4) = *(const float4*)&outv[4];
    *(u16x8*)(xb + off) = ob;
}

// ---------------------------------------------------------------------------
extern "C" void kernel_launch(void* const* d_in, const int* in_sizes, int n_in,
                              void* d_out, int out_size, void* d_ws, size_t ws_size,
                              hipStream_t stream)
{
    const int*   targets = (const int*)  d_in[0];
    const float* memory  = (const float*)d_in[1];
    // d_in[2]=trg_mask (causal, analytic), d_in[3]=memory_mask (all false) -> unread
    const float* emb     = (const float*)d_in[4];
    const float* Wg[8]; for (int i = 0; i < 8; ++i) Wg[i] = (const float*)d_in[5 + i];
    const float* bg[8]; for (int i = 0; i < 8; ++i) bg[i] = (const float*)d_in[13 + i];
    const float* W1  = (const float*)d_in[21];
    const float* b1  = (const float*)d_in[22];
    const float* W2  = (const float*)d_in[23];
    const float* b2  = (const float*)d_in[24];
    const float* g1  = (const float*)d_in[25];
    const float* g2  = (const float*)d_in[26];
    const float* g3  = (const float*)d_in[27];
    const float* be1 = (const float*)d_in[28];
    const float* be2 = (const float*)d_in[29];
    const float* be3 = (const float*)d_in[30];

    char* w = (char*)d_ws;
    auto take = [&](size_t n) -> char* { char* p = w; w += (n + 255) & ~(size_t)255; return p; };
    u16*   wqkvT = (u16*)take((size_t)NLAY * 3 * DIM * DIM * 2);   // [L][1536][512]
    u16*   wkvcT = (u16*)take((size_t)NLAY * 2 * DIM * DIM * 2);   // [L][1024][512]
    u16*   wqcT  = (u16*)take((size_t)NLAY * DIM * DIM * 2);
    u16*   woT   = (u16*)take((size_t)NLAY * DIM * DIM * 2);
    u16*   wocT  = (u16*)take((size_t)NLAY * DIM * DIM * 2);
    u16*   w1T   = (u16*)take((size_t)NLAY * DIM * DFFN * 2);      // [L][2048][512]
    u16*   w2T   = (u16*)take((size_t)NLAY * DIM * DFFN * 2);      // [L][512][2048]
    float* bqkv  = (float*)take((size_t)NLAY * 3 * DIM * 4);
    float* bkvc  = (float*)take((size_t)NLAY * 2 * DIM * 4);
    float* x     = (float*)take((size_t)MROWS * DIM * 4);
    float* y     = (float*)take((size_t)MROWS * DIM * 4);
    u16*   xb    = (u16*)  take((size_t)MROWS * DIM * 2);
    u16*   memb  = (u16*)  take((size_t)MROWS * DIM * 2);
    u16*   qh    = (u16*)  take((size_t)MROWS * DIM * 2);
    u16*   kh    = (u16*)  take((size_t)MROWS * DIM * 2);
    u16*   vT    = (u16*)  take((size_t)MROWS * DIM * 2);
    u16*   ctx   = (u16*)  take((size_t)MROWS * DIM * 2);
    u16*   att   = (u16*)  take((size_t)BATCH * NHEAD * SEQ * SEQ * 2);
    u16*   h1    = att;   // FFN hidden (16MB) aliases attention buffer: disjoint lifetimes

    const long SQ = (long)DIM * DIM;  // 262144
    transpose_w<<<dim3(16, 16, NLAY), 256, 0, stream>>>(Wg[0], wqkvT,          DIM, DIM, 3 * SQ);
    transpose_w<<<dim3(16, 16, NLAY), 256, 0, stream>>>(Wg[1], wqkvT + SQ,     DIM, DIM, 3 * SQ);
    transpose_w<<<dim3(16, 16, NLAY), 256, 0, stream>>>(Wg[2], wqkvT + 2 * SQ, DIM, DIM, 3 * SQ);
    transpose_w<<<dim3(16, 16, NLAY), 256, 0, stream>>>(Wg[3], woT,            DIM, DIM, SQ);
    transpose_w<<<dim3(16, 16, NLAY), 256, 0, stream>>>(Wg[4], wqcT,           DIM, DIM, SQ);
    transpose_w<<<dim3(16, 16, NLAY), 256, 0, stream>>>(Wg[5], wkvcT,          DIM, DIM, 2 * SQ);
    transpose_w<<<dim3(16, 16, NLAY), 256, 0, stream>>>(Wg[6], wkvcT + SQ,     DIM, DIM, 2 * SQ);
    transpose_w<<<dim3(16, 16, NLAY), 256, 0, stream>>>(Wg[7], wocT,           DIM, DIM, SQ);
    transpose_w<<<dim3(64, 16, NLAY), 256, 0, stream>>>(W1, w1T, DIM, DFFN, (long)DIM * DFFN);
    transpose_w<<<dim3(16, 64, NLAY), 256, 0, stream>>>(W2, w2T, DFFN, DIM, (long)DIM * DFFN);
    concat_bias<<<NLAY * 3 * DIM / 256, 256, 0, stream>>>(bg[0], bg[1], bg[2], bqkv, 3);
    concat_bias<<<NLAY * 2 * DIM / 256, 256, 0, stream>>>(bg[5], bg[6], nullptr, bkvc, 2);
    conv_f32_bf16<<<2048, 256, 0, stream>>>(memory, memb);
    embed_pe<<<2048, 256, 0, stream>>>(targets, emb, x, xb);

    for (int i = 0; i < NLAY; ++i) {
        const u16 *wqkv = wqkvT + (long)i * 3 * SQ, *wkvc = wkvcT + (long)i * 2 * SQ;
        const u16 *wqc = wqcT + (long)i * SQ, *wo = woT + (long)i * SQ, *woc = wocT + (long)i * SQ;
        const u16 *w1t = w1T + (long)i * DIM * DFFN, *w2t = w2T + (long)i * DIM * DFFN;
        const float *bo = bg[3] + i * DIM, *bqc = bg[4] + i * DIM, *boc = bg[7] + i * DIM;

        // ---- self attention (causal) ----
        gemm_glds<128, 4><<<dim3(12, 32), 256, 0, stream>>>(xb, wqkv, qh, kh, vT, bqkv + i * 3 * DIM, DIM, 0);
        gemm_bt<1, false, false><<<dim3(8, 8, 64), 256, 0, stream>>>(qh, kh, att, nullptr, SEQ, SEQ, DHEAD, HD, HD, SS, 0, 1, SEQ);
        softmax_rows<<<(BATCH * NHEAD * SEQ) / 4, 256, 0, stream>>>(att, 1);
        gemm_bt<1, false, false><<<dim3(1, 8, 64), 256, 0, stream>>>(att, vT, ctx, nullptr, SEQ, DHEAD, SEQ, SS, HD, (long)SEQ * DIM, DHEAD, NHEAD, DIM);
        gemm_glds<64, 0><<<dim3(8, 32), 256, 0, stream>>>(ctx, wo, y, nullptr, nullptr, bo, DIM, DIM);
        add_ln<<<MROWS / 4, 256, 0, stream>>>(x, y, x, xb, g1 + i * DIM, be1 + i * DIM);

        // ---- cross attention (no mask) ----
        gemm_glds<64, 2><<<dim3(8, 32), 256, 0, stream>>>(xb, wqc, qh, nullptr, nullptr, bqc, DIM, 0);
        gemm_glds<128, 3><<<dim3(8, 32), 256, 0, stream>>>(memb, wkvc, nullptr, kh, vT, bkvc + i * 2 * DIM, DIM, 0);
        gemm_bt<1, false, false><<<dim3(8, 8, 64), 256, 0, stream>>>(qh, kh, att, nullptr, SEQ, SEQ, DHEAD, HD, HD, SS, 0, 1, SEQ);
        softmax_rows<<<(BATCH * NHEAD * SEQ) / 4, 256, 0, stream>>>(att, 0);
        gemm_bt<1, false, false><<<dim3(1, 8, 64), 256, 0, stream>>>(att, vT, ctx, nullptr, SEQ, DHEAD, SEQ, SS, HD, (long)SEQ * DIM, DHEAD, NHEAD, DIM);
        gemm_glds<64, 0><<<dim3(8, 32), 256, 0, stream>>>(ctx, woc, y, nullptr, nullptr, boc, DIM, DIM);
        add_ln<<<MROWS / 4, 256, 0, stream>>>(x, y, x, xb, g2 + i * DIM, be2 + i * DIM);

        // ---- FFN ----
        gemm_glds<128, 1><<<dim3(16, 32), 256, 0, stream>>>(xb, w1t, h1, nullptr, nullptr, b1 + i * DFFN, DIM, DFFN);
        gemm_glds<64, 0><<<dim3(8, 32), 256, 0, stream>>>(h1, w2t, y, nullptr, nullptr, b2 + i * DIM, DFFN, DIM);
        float* xo = (i == NLAY - 1) ? (float*)d_out : x;
        add_ln<<<MROWS / 4, 256, 0, stream>>>(x, y, xo, xb, g3 + i * DIM, be3 + i * DIM);
    }
}

// Round 3
// 1360.778 us; speedup vs baseline: 1.1975x; 1.1975x over previous
//
#include <hip/hip_runtime.h>

typedef unsigned short u16;
typedef unsigned int   u32;
typedef __attribute__((ext_vector_type(4))) u16   u16x4;
typedef __attribute__((ext_vector_type(8))) u16   u16x8;
typedef __attribute__((ext_vector_type(8))) __bf16 bf16x8;
typedef __attribute__((ext_vector_type(4))) float f32x4;

#define DEV static __device__ __forceinline__

constexpr int DIM = 512, NHEAD = 8, DHEAD = 64, DFFN = 2048, NLAY = 6, SEQ = 512, BATCH = 8;
constexpr int MROWS = BATCH * SEQ;            // 4096 token rows
constexpr long HD = (long)SEQ * DHEAD;        // 32768 per-head q/k/v block
constexpr long SS = (long)SEQ * SEQ;          // 262144 per-head score block

DEV float bf2f(u16 u) { union { u32 i; float f; } x; x.i = (u32)u << 16; return x.f; }
DEV u16 f2bf(float f) { union { float f; u32 i; } x; x.f = f; u32 r = x.i + 0x7fffu + ((x.i >> 16) & 1u); return (u16)(r >> 16); }

DEV void gl_lds16(const u16* g, u16* l) {
    __builtin_amdgcn_global_load_lds((const __attribute__((address_space(1))) u32*)(const void*)g,
                                     (__attribute__((address_space(3))) u32*)(void*)l, 16, 0, 0);
}

// ---------------------------------------------------------------------------
// Weight transpose + f32->bf16:  out[z*outLS + n*K + k] = bf16(in[z*K*N + k*N + n])
// ---------------------------------------------------------------------------
__global__ __launch_bounds__(256) void transpose_w(const float* __restrict__ in, u16* __restrict__ out,
                                                   int K, int N, long outLS)
{
    __shared__ u16 t[32][33];
    long bi = (long)blockIdx.z * K * N, bo = (long)blockIdx.z * outLS;
    int k0 = blockIdx.y * 32, n0 = blockIdx.x * 32;
    int tx = threadIdx.x & 31, ty = threadIdx.x >> 5;
    #pragma unroll
    for (int i = ty; i < 32; i += 8) t[i][tx] = f2bf(in[bi + (long)(k0 + i) * N + n0 + tx]);
    __syncthreads();
    #pragma unroll
    for (int i = ty; i < 32; i += 8) out[bo + (long)(n0 + i) * K + k0 + tx] = t[tx][i];
}

// concat per-layer bias vectors (each NLAY x 512) into [NLAY][nsrc*512]
__global__ __launch_bounds__(256) void concat_bias(const float* __restrict__ a, const float* __restrict__ b,
                                                   const float* __restrict__ c, float* __restrict__ out, int nsrc)
{
    int i = blockIdx.x * 256 + threadIdx.x;
    int col = i & 511, j = (i >> 9) % nsrc, l = i / (nsrc * 512);
    const float* s = (j == 0) ? a : (j == 1) ? b : c;
    out[i] = s[l * 512 + col];
}

__global__ __launch_bounds__(256) void conv_f32_bf16(const float* __restrict__ in, u16* __restrict__ out)
{
    long i = ((long)blockIdx.x * 256 + threadIdx.x) * 4;
    float4 v = *(const float4*)(in + i);
    u16x4 o; o.x = f2bf(v.x); o.y = f2bf(v.y); o.z = f2bf(v.z); o.w = f2bf(v.w);
    *(u16x4*)(out + i) = o;
}

// ---------------------------------------------------------------------------
// Embedding * sqrt(D) + sinusoidal positional encoding -> x (f32) and xb (bf16)
// ---------------------------------------------------------------------------
__global__ __launch_bounds__(256) void embed_pe(const int* __restrict__ targets, const float* __restrict__ emb,
                                                float* __restrict__ x, u16* __restrict__ xb)
{
    int t4 = (blockIdx.x * 256 + threadIdx.x) * 4;
    int d = t4 & (DIM - 1);
    int s = (t4 >> 9) & (SEQ - 1);
    int b = t4 >> 18;
    int tok = targets[s * BATCH + b];
    float4 e = *(const float4*)(emb + (long)tok * DIM + d);
    float o[4]; u16x4 ob;
    const float ef[4] = { e.x, e.y, e.z, e.w };
    #pragma unroll
    for (int j = 0; j < 4; ++j) {
        int dd = d + j;
        float div = expf((float)(dd & ~1) * -0.017988946039016f);  // -ln(10000)/512
        float ang = (float)s * div;
        float pe = (dd & 1) ? cosf(ang) : sinf(ang);
        float val = ef[j] * 22.627416997969522f + pe;              // sqrt(512)
        o[j] = val; ob[j] = f2bf(val);
    }
    long idx = ((long)b * SEQ + s) * DIM + d;
    *(float4*)(x + idx) = *(const float4*)o;
    *(u16x4*)(xb + idx) = ob;
}

// scatter helpers: (B*S, D)-indexed value -> head-split layouts
DEV void scat_sd(u16* dst, int mm, int col, float v) {   // (B,NH,S,DH)
    dst[(long)((mm >> 9) * NHEAD + (col >> 6)) * HD + (long)(mm & 511) * DHEAD + (col & 63)] = f2bf(v);
}
DEV void scat_ds(u16* dst, int mm, int col, float v) {   // (B,NH,DH,S)
    dst[(long)((mm >> 9) * NHEAD + (col >> 6)) * HD + (long)(col & 63) * SEQ + (mm & 511)] = f2bf(v);
}

// ---------------------------------------------------------------------------
// m97-structure GEMM: C = A @ Bt^T + bias. A: MxK bf16, Bt: NxK bf16.
// BM x BN tile, BK=32, 4 waves (wave tile BM/2 x BN/2), global_load_lds
// width-16 into linear LDS, double-buffered, one barrier per K-step.
// 1D grid, bijective XCD-chunk swizzle (requires gridDim.x % 8 == 0):
// consecutive same-A-row-panel blocks land on one XCD -> A fetched once/XCD.
// EPI: 0=f32 (ldc), 1=bf16+relu (ldc), 2=Q scatter, 3=KV scatter, 4=QKV scatter
// ---------------------------------------------------------------------------
template <int BM, int BN, int EPI>
__global__ __launch_bounds__(256) void gemm_glds(const u16* __restrict__ A, const u16* __restrict__ Bt,
                                                 void* __restrict__ C0, void* __restrict__ C1, void* __restrict__ C2,
                                                 const float* __restrict__ bias, int K, int ldc, int gx)
{
    constexpr int NCHA = BM / 16;        // A chunks of 16 rows
    constexpr int NCH  = NCHA + BN / 16; // total chunks per buffer
    constexpr int MI   = BM / 32;        // M fragments per wave
    constexpr int NI   = BN / 32;        // N fragments per wave
    __shared__ __align__(16) u16 lds[2][NCH * 512];

    const int tid = threadIdx.x, lane = tid & 63, wid = tid >> 6;
    const int nwg = gridDim.x, bid = blockIdx.x;
    const int wg = (bid & 7) * (nwg >> 3) + (bid >> 3);     // XCD-chunk swizzle
    const int m0 = (wg / gx) * BM, n0 = (wg % gx) * BN;
    const int wr = (wid >> 1) * (BM / 2), wc = (wid & 1) * (BN / 2);
    const int fr = lane & 15, fq = lane >> 4, kg = fq * 8;
    const int srow = lane >> 2, scol = (lane & 3) * 8;      // staging lane map

    f32x4 acc[MI][NI] = {};

    auto stage = [&](int buf, int k0) {
        for (int c = wid; c < NCH; c += 4) {
            if (c < NCHA) gl_lds16(A  + (long)(m0 + c * 16 + srow) * K + k0 + scol, &lds[buf][c * 512]);
            else          gl_lds16(Bt + (long)(n0 + (c - NCHA) * 16 + srow) * K + k0 + scol, &lds[buf][c * 512]);
        }
    };

    const int nt = K >> 5;
    stage(0, 0);
    __syncthreads();                        // drains vmcnt(0): buf0 ready
    int cur = 0;
    for (int t = 0; t < nt; ++t) {
        if (t + 1 < nt) stage(cur ^ 1, (t + 1) << 5);
        bf16x8 af[MI], bfv[NI];
        #pragma unroll
        for (int mi = 0; mi < MI; ++mi)
            af[mi] = *(const bf16x8*)&lds[cur][(wr + mi * 16 + fr) * 32 + kg];
        #pragma unroll
        for (int ni = 0; ni < NI; ++ni)
            bfv[ni] = *(const bf16x8*)&lds[cur][BM * 32 + (wc + ni * 16 + fr) * 32 + kg];
        #pragma unroll
        for (int mi = 0; mi < MI; ++mi)
            #pragma unroll
            for (int ni = 0; ni < NI; ++ni)
                acc[mi][ni] = __builtin_amdgcn_mfma_f32_16x16x32_bf16(af[mi], bfv[ni], acc[mi][ni], 0, 0, 0);
        __syncthreads();                    // drains prefetch vmcnt + lgkm, then barrier
        cur ^= 1;
    }

    #pragma unroll
    for (int mi = 0; mi < MI; ++mi)
    #pragma unroll
    for (int ni = 0; ni < NI; ++ni)
    #pragma unroll
    for (int rr = 0; rr < 4; ++rr) {
        int mm = m0 + wr + mi * 16 + fq * 4 + rr;
        int nn = n0 + wc + ni * 16 + fr;
        float v = acc[mi][ni][rr] + bias[nn];
        if (EPI == 0) {
            ((float*)C0)[(long)mm * ldc + nn] = v;
        } else if (EPI == 1) {
            ((u16*)C0)[(long)mm * ldc + nn] = f2bf(fmaxf(v, 0.f));
        } else if (EPI == 2) {
            scat_sd((u16*)C0, mm, nn, v);
        } else if (EPI == 3) {
            if (nn < 512) scat_sd((u16*)C1, mm, nn, v);
            else          scat_ds((u16*)C2, mm, nn - 512, v);
        } else {            // QKV
            int which = nn >> 9, col = nn & 511;
            if (which == 0)      scat_sd((u16*)C0, mm, col, v);
            else if (which == 1) scat_sd((u16*)C1, mm, col, v);
            else                 scat_ds((u16*)C2, mm, col, v);
        }
    }
}

// ---------------------------------------------------------------------------
// Batched 64x64-tile GEMM for attention scores / PV.
// C batch offset: (z/cDiv)*cOut + (z%cDiv)*cIn. bf16 output.
// ---------------------------------------------------------------------------
__global__ __launch_bounds__(256) void gemm_bt(const u16* __restrict__ A, const u16* __restrict__ Bt,
                                               void* __restrict__ C,
                                               int M, int N, int K,
                                               long aB, long bB, long cOut, long cIn, int cDiv, int ldc)
{
    __shared__ __align__(16) u16 As[64][40];
    __shared__ __align__(16) u16 Bs[64][40];
    const int tid = threadIdx.x, lane = tid & 63, wid = tid >> 6;
    const int m0 = blockIdx.y * 64, n0 = blockIdx.x * 64, z = blockIdx.z;
    const u16* Ab = A + (long)z * aB;
    const u16* Bb = Bt + (long)z * bB;
    const int r  = tid >> 2, c4 = (tid & 3) * 8;
    const int wr = (wid >> 1) * 32, wc = (wid & 1) * 32;
    const int fr = lane & 15, kg = (lane >> 4) * 8, fq = lane >> 4;

    f32x4 acc[2][2] = {};
    u16x8 av = *(const u16x8*)(Ab + (long)(m0 + r) * K + c4);
    u16x8 bv = *(const u16x8*)(Bb + (long)(n0 + r) * K + c4);

    for (int k0 = 0; k0 < K; k0 += 32) {
        __syncthreads();
        *(u16x8*)&As[r][c4] = av;
        *(u16x8*)&Bs[r][c4] = bv;
        if (k0 + 32 < K) {
            av = *(const u16x8*)(Ab + (long)(m0 + r) * K + (k0 + 32) + c4);
            bv = *(const u16x8*)(Bb + (long)(n0 + r) * K + (k0 + 32) + c4);
        }
        __syncthreads();
        bf16x8 a0 = *(const bf16x8*)&As[wr + fr][kg];
        bf16x8 a1 = *(const bf16x8*)&As[wr + 16 + fr][kg];
        bf16x8 b0 = *(const bf16x8*)&Bs[wc + fr][kg];
        bf16x8 b1 = *(const bf16x8*)&Bs[wc + 16 + fr][kg];
        acc[0][0] = __builtin_amdgcn_mfma_f32_16x16x32_bf16(a0, b0, acc[0][0], 0, 0, 0);
        acc[0][1] = __builtin_amdgcn_mfma_f32_16x16x32_bf16(a0, b1, acc[0][1], 0, 0, 0);
        acc[1][0] = __builtin_amdgcn_mfma_f32_16x16x32_bf16(a1, b0, acc[1][0], 0, 0, 0);
        acc[1][1] = __builtin_amdgcn_mfma_f32_16x16x32_bf16(a1, b1, acc[1][1], 0, 0, 0);
    }

    const long cb = (long)(z / cDiv) * cOut + (long)(z % cDiv) * cIn;
    #pragma unroll
    for (int mi = 0; mi < 2; ++mi)
    #pragma unroll
    for (int ni = 0; ni < 2; ++ni)
    #pragma unroll
    for (int rr = 0; rr < 4; ++rr) {
        int mm = m0 + wr + mi * 16 + fq * 4 + rr;
        int nn = n0 + wc + ni * 16 + fr;
        ((u16*)C)[cb + (long)mm * ldc + nn] = f2bf(acc[mi][ni][rr]);
    }
}

// ---------------------------------------------------------------------------
// Row softmax over bf16 scores (in-place), scale 1/8, optional causal mask.
// ---------------------------------------------------------------------------
__global__ __launch_bounds__(256) void softmax_rows(u16* __restrict__ att, int causal)
{
    int row = blockIdx.x * 4 + (threadIdx.x >> 6);
    int lane = threadIdx.x & 63;
    int q = row & (SEQ - 1);
    u16* p = att + (long)row * SEQ + lane * 8;
    u16x8 v = *(u16x8*)p;
    float f[8], mx = -3.0e38f;
    #pragma unroll
    for (int j = 0; j < 8; ++j) {
        int col = lane * 8 + j;
        float s = bf2f(v[j]) * 0.125f;               // 1/sqrt(64)
        if (causal && col > q) s = -3.0e38f;
        f[j] = s; mx = fmaxf(mx, s);
    }
    #pragma unroll
    for (int o = 32; o; o >>= 1) mx = fmaxf(mx, __shfl_xor(mx, o, 64));
    float sum = 0.f;
    #pragma unroll
    for (int j = 0; j < 8; ++j) { f[j] = __expf(f[j] - mx); sum += f[j]; }
    #pragma unroll
    for (int o = 32; o; o >>= 1) sum += __shfl_xor(sum, o, 64);
    float inv = 1.0f / sum;
    u16x8 ov;
    #pragma unroll
    for (int j = 0; j < 8; ++j) ov[j] = f2bf(f[j] * inv);
    *(u16x8*)p = ov;
}

// ---------------------------------------------------------------------------
// x = LayerNorm(x + y) * g + be;  writes f32 (xo) and bf16 (xb).
// ---------------------------------------------------------------------------
__global__ __launch_bounds__(256) void add_ln(const float* x, const float* __restrict__ y,
                                              float* xo, u16* __restrict__ xb,
                                              const float* __restrict__ g, const float* __restrict__ be)
{
    int row = blockIdx.x * 4 + (threadIdx.x >> 6);
    int lane = threadIdx.x & 63;
    long off = (long)row * DIM + lane * 8;
    float v[8];
    {
        float4 a0 = *(const float4*)(x + off);
        float4 a1 = *(const float4*)(x + off + 4);
        float4 b0 = *(const float4*)(y + off);
        float4 b1 = *(const float4*)(y + off + 4);
        v[0] = a0.x + b0.x; v[1] = a0.y + b0.y; v[2] = a0.z + b0.z; v[3] = a0.w + b0.w;
        v[4] = a1.x + b1.x; v[5] = a1.y + b1.y; v[6] = a1.z + b1.z; v[7] = a1.w + b1.w;
    }
    float sum = 0.f;
    #pragma unroll
    for (int j = 0; j < 8; ++j) sum += v[j];
    #pragma unroll
    for (int o = 32; o; o >>= 1) sum += __shfl_xor(sum, o, 64);
    float mean = sum * (1.0f / DIM);
    float vs = 0.f;
    #pragma unroll
    for (int j = 0; j < 8; ++j) { float d = v[j] - mean; vs += d * d; }
    #pragma unroll
    for (int o = 32; o; o >>= 1) vs += __shfl_xor(vs, o, 64);
    float rstd = rsqrtf(vs * (1.0f / DIM) + 1e-5f);
    float outv[8]; u16x8 ob;
    #pragma unroll
    for (int j = 0; j < 8; ++j) {
        int col = lane * 8 + j;
        float r = (v[j] - mean) * rstd * g[col] + be[col];
        outv[j] = r; ob[j] = f2bf(r);
    }
    *(float4*)(xo + off)     = *(const float4*)&outv[0];
    *(float4*)(xo + off + 4) = *(const float4*)&outv[4];
    *(u16x8*)(xb + off) = ob;
}

// ---------------------------------------------------------------------------
extern "C" void kernel_launch(void* const* d_in, const int* in_sizes, int n_in,
                              void* d_out, int out_size, void* d_ws, size_t ws_size,
                              hipStream_t stream)
{
    const int*   targets = (const int*)  d_in[0];
    const float* memory  = (const float*)d_in[1];
    // d_in[2]=trg_mask (causal, analytic), d_in[3]=memory_mask (all false) -> unread
    const float* emb     = (const float*)d_in[4];
    const float* Wg[8]; for (int i = 0; i < 8; ++i) Wg[i] = (const float*)d_in[5 + i];
    const float* bg[8]; for (int i = 0; i < 8; ++i) bg[i] = (const float*)d_in[13 + i];
    const float* W1  = (const float*)d_in[21];
    const float* b1  = (const float*)d_in[22];
    const float* W2  = (const float*)d_in[23];
    const float* b2  = (const float*)d_in[24];
    const float* g1  = (const float*)d_in[25];
    const float* g2  = (const float*)d_in[26];
    const float* g3  = (const float*)d_in[27];
    const float* be1 = (const float*)d_in[28];
    const float* be2 = (const float*)d_in[29];
    const float* be3 = (const float*)d_in[30];

    char* w = (char*)d_ws;
    auto take = [&](size_t n) -> char* { char* p = w; w += (n + 255) & ~(size_t)255; return p; };
    u16*   wqkvT = (u16*)take((size_t)NLAY * 3 * DIM * DIM * 2);   // [L][1536][512]
    u16*   wkvcT = (u16*)take((size_t)NLAY * 2 * DIM * DIM * 2);   // [L][1024][512]
    u16*   wqcT  = (u16*)take((size_t)NLAY * DIM * DIM * 2);
    u16*   woT   = (u16*)take((size_t)NLAY * DIM * DIM * 2);
    u16*   wocT  = (u16*)take((size_t)NLAY * DIM * DIM * 2);
    u16*   w1T   = (u16*)take((size_t)NLAY * DIM * DFFN * 2);      // [L][2048][512]
    u16*   w2T   = (u16*)take((size_t)NLAY * DIM * DFFN * 2);      // [L][512][2048]
    float* bqkv  = (float*)take((size_t)NLAY * 3 * DIM * 4);
    float* bkvc  = (float*)take((size_t)NLAY * 2 * DIM * 4);
    float* x     = (float*)take((size_t)MROWS * DIM * 4);
    float* y     = (float*)take((size_t)MROWS * DIM * 4);
    u16*   xb    = (u16*)  take((size_t)MROWS * DIM * 2);
    u16*   memb  = (u16*)  take((size_t)MROWS * DIM * 2);
    u16*   qh    = (u16*)  take((size_t)MROWS * DIM * 2);
    u16*   kh    = (u16*)  take((size_t)MROWS * DIM * 2);
    u16*   vT    = (u16*)  take((size_t)MROWS * DIM * 2);
    u16*   ctx   = (u16*)  take((size_t)MROWS * DIM * 2);
    u16*   att   = (u16*)  take((size_t)BATCH * NHEAD * SEQ * SEQ * 2);
    u16*   h1    = att;   // FFN hidden (16MB) aliases attention buffer: disjoint lifetimes

    const long SQ = (long)DIM * DIM;  // 262144
    transpose_w<<<dim3(16, 16, NLAY), 256, 0, stream>>>(Wg[0], wqkvT,          DIM, DIM, 3 * SQ);
    transpose_w<<<dim3(16, 16, NLAY), 256, 0, stream>>>(Wg[1], wqkvT + SQ,     DIM, DIM, 3 * SQ);
    transpose_w<<<dim3(16, 16, NLAY), 256, 0, stream>>>(Wg[2], wqkvT + 2 * SQ, DIM, DIM, 3 * SQ);
    transpose_w<<<dim3(16, 16, NLAY), 256, 0, stream>>>(Wg[3], woT,            DIM, DIM, SQ);
    transpose_w<<<dim3(16, 16, NLAY), 256, 0, stream>>>(Wg[4], wqcT,           DIM, DIM, SQ);
    transpose_w<<<dim3(16, 16, NLAY), 256, 0, stream>>>(Wg[5], wkvcT,          DIM, DIM, 2 * SQ);
    transpose_w<<<dim3(16, 16, NLAY), 256, 0, stream>>>(Wg[6], wkvcT + SQ,     DIM, DIM, 2 * SQ);
    transpose_w<<<dim3(16, 16, NLAY), 256, 0, stream>>>(Wg[7], wocT,           DIM, DIM, SQ);
    transpose_w<<<dim3(64, 16, NLAY), 256, 0, stream>>>(W1, w1T, DIM, DFFN, (long)DIM * DFFN);
    transpose_w<<<dim3(16, 64, NLAY), 256, 0, stream>>>(W2, w2T, DFFN, DIM, (long)DIM * DFFN);
    concat_bias<<<NLAY * 3 * DIM / 256, 256, 0, stream>>>(bg[0], bg[1], bg[2], bqkv, 3);
    concat_bias<<<NLAY * 2 * DIM / 256, 256, 0, stream>>>(bg[5], bg[6], nullptr, bkvc, 2);
    conv_f32_bf16<<<2048, 256, 0, stream>>>(memory, memb);
    embed_pe<<<2048, 256, 0, stream>>>(targets, emb, x, xb);

    for (int i = 0; i < NLAY; ++i) {
        const u16 *wqkv = wqkvT + (long)i * 3 * SQ, *wkvc = wkvcT + (long)i * 2 * SQ;
        const u16 *wqc = wqcT + (long)i * SQ, *wo = woT + (long)i * SQ, *woc = wocT + (long)i * SQ;
        const u16 *w1t = w1T + (long)i * DIM * DFFN, *w2t = w2T + (long)i * DIM * DFFN;
        const float *bo = bg[3] + i * DIM, *bqc = bg[4] + i * DIM, *boc = bg[7] + i * DIM;

        // ---- self attention (causal) ----
        gemm_glds<64, 128, 4><<<768, 256, 0, stream>>>(xb, wqkv, qh, kh, vT, bqkv + i * 3 * DIM, DIM, 0, 12);
        gemm_bt<<<dim3(8, 8, 64), 256, 0, stream>>>(qh, kh, att, SEQ, SEQ, DHEAD, HD, HD, SS, 0, 1, SEQ);
        softmax_rows<<<(BATCH * NHEAD * SEQ) / 4, 256, 0, stream>>>(att, 1);
        gemm_bt<<<dim3(1, 8, 64), 256, 0, stream>>>(att, vT, ctx, SEQ, DHEAD, SEQ, SS, HD, (long)SEQ * DIM, DHEAD, NHEAD, DIM);
        gemm_glds<64, 64, 0><<<512, 256, 0, stream>>>(ctx, wo, y, nullptr, nullptr, bo, DIM, DIM, 8);
        add_ln<<<MROWS / 4, 256, 0, stream>>>(x, y, x, xb, g1 + i * DIM, be1 + i * DIM);

        // ---- cross attention (no mask) ----
        gemm_glds<64, 64, 2><<<512, 256, 0, stream>>>(xb, wqc, qh, nullptr, nullptr, bqc, DIM, 0, 8);
        gemm_glds<64, 128, 3><<<512, 256, 0, stream>>>(memb, wkvc, nullptr, kh, vT, bkvc + i * 2 * DIM, DIM, 0, 8);
        gemm_bt<<<dim3(8, 8, 64), 256, 0, stream>>>(qh, kh, att, SEQ, SEQ, DHEAD, HD, HD, SS, 0, 1, SEQ);
        softmax_rows<<<(BATCH * NHEAD * SEQ) / 4, 256, 0, stream>>>(att, 0);
        gemm_bt<<<dim3(1, 8, 64), 256, 0, stream>>>(att, vT, ctx, SEQ, DHEAD, SEQ, SS, HD, (long)SEQ * DIM, DHEAD, NHEAD, DIM);
        gemm_glds<64, 64, 0><<<512, 256, 0, stream>>>(ctx, woc, y, nullptr, nullptr, boc, DIM, DIM, 8);
        add_ln<<<MROWS / 4, 256, 0, stream>>>(x, y, x, xb, g2 + i * DIM, be2 + i * DIM);

        // ---- FFN ----
        gemm_glds<64, 128, 1><<<1024, 256, 0, stream>>>(xb, w1t, h1, nullptr, nullptr, b1 + i * DFFN, DIM, DFFN, 16);
        gemm_glds<64, 64, 0><<<512, 256, 0, stream>>>(h1, w2t, y, nullptr, nullptr, b2 + i * DIM, DFFN, DIM, 8);
        float* xo = (i == NLAY - 1) ? (float*)d_out : x;
        add_ln<<<MROWS / 4, 256, 0, stream>>>(x, y, xo, xb, g3 + i * DIM, be3 + i * DIM);
    }
}

// Round 4
// 1212.313 us; speedup vs baseline: 1.3441x; 1.1225x over previous
//
#include <hip/hip_runtime.h>

typedef unsigned short u16;
typedef unsigned int   u32;
typedef __attribute__((ext_vector_type(4))) u16   u16x4;
typedef __attribute__((ext_vector_type(8))) u16   u16x8;
typedef __attribute__((ext_vector_type(8))) __bf16 bf16x8;
typedef __attribute__((ext_vector_type(4))) float f32x4;

#define DEV static __device__ __forceinline__

constexpr int DIM = 512, NHEAD = 8, DHEAD = 64, DFFN = 2048, NLAY = 6, SEQ = 512, BATCH = 8;
constexpr int MROWS = BATCH * SEQ;            // 4096 token rows
constexpr long HD = (long)SEQ * DHEAD;        // 32768 per-head q/k/v block

DEV float bf2f(u16 u) { union { u32 i; float f; } x; x.i = (u32)u << 16; return x.f; }
DEV u16 f2bf(float f) { union { float f; u32 i; } x; x.f = f; u32 r = x.i + 0x7fffu + ((x.i >> 16) & 1u); return (u16)(r >> 16); }

DEV void gl_lds16(const u16* g, u16* l) {
    __builtin_amdgcn_global_load_lds((const __attribute__((address_space(1))) u32*)(const void*)g,
                                     (__attribute__((address_space(3))) u32*)(void*)l, 16, 0, 0);
}

// ---------------------------------------------------------------------------
// Weight transpose + f32->bf16:  out[z*outLS + n*K + k] = bf16(in[z*K*N + k*N + n])
// ---------------------------------------------------------------------------
__global__ __launch_bounds__(256) void transpose_w(const float* __restrict__ in, u16* __restrict__ out,
                                                   int K, int N, long outLS)
{
    __shared__ u16 t[32][33];
    long bi = (long)blockIdx.z * K * N, bo = (long)blockIdx.z * outLS;
    int k0 = blockIdx.y * 32, n0 = blockIdx.x * 32;
    int tx = threadIdx.x & 31, ty = threadIdx.x >> 5;
    #pragma unroll
    for (int i = ty; i < 32; i += 8) t[i][tx] = f2bf(in[bi + (long)(k0 + i) * N + n0 + tx]);
    __syncthreads();
    #pragma unroll
    for (int i = ty; i < 32; i += 8) out[bo + (long)(n0 + i) * K + k0 + tx] = t[tx][i];
}

// concat per-layer bias vectors (each NLAY x 512) into [NLAY][nsrc*512]
__global__ __launch_bounds__(256) void concat_bias(const float* __restrict__ a, const float* __restrict__ b,
                                                   const float* __restrict__ c, float* __restrict__ out, int nsrc)
{
    int i = blockIdx.x * 256 + threadIdx.x;
    int col = i & 511, j = (i >> 9) % nsrc, l = i / (nsrc * 512);
    const float* s = (j == 0) ? a : (j == 1) ? b : c;
    out[i] = s[l * 512 + col];
}

__global__ __launch_bounds__(256) void conv_f32_bf16(const float* __restrict__ in, u16* __restrict__ out)
{
    long i = ((long)blockIdx.x * 256 + threadIdx.x) * 4;
    float4 v = *(const float4*)(in + i);
    u16x4 o; o.x = f2bf(v.x); o.y = f2bf(v.y); o.z = f2bf(v.z); o.w = f2bf(v.w);
    *(u16x4*)(out + i) = o;
}

// ---------------------------------------------------------------------------
// Embedding * sqrt(D) + sinusoidal positional encoding -> x (f32) and xb (bf16)
// ---------------------------------------------------------------------------
__global__ __launch_bounds__(256) void embed_pe(const int* __restrict__ targets, const float* __restrict__ emb,
                                                float* __restrict__ x, u16* __restrict__ xb)
{
    int t4 = (blockIdx.x * 256 + threadIdx.x) * 4;
    int d = t4 & (DIM - 1);
    int s = (t4 >> 9) & (SEQ - 1);
    int b = t4 >> 18;
    int tok = targets[s * BATCH + b];
    float4 e = *(const float4*)(emb + (long)tok * DIM + d);
    float o[4]; u16x4 ob;
    const float ef[4] = { e.x, e.y, e.z, e.w };
    #pragma unroll
    for (int j = 0; j < 4; ++j) {
        int dd = d + j;
        float div = expf((float)(dd & ~1) * -0.017988946039016f);  // -ln(10000)/512
        float ang = (float)s * div;
        float pe = (dd & 1) ? cosf(ang) : sinf(ang);
        float val = ef[j] * 22.627416997969522f + pe;              // sqrt(512)
        o[j] = val; ob[j] = f2bf(val);
    }
    long idx = ((long)b * SEQ + s) * DIM + d;
    *(float4*)(x + idx) = *(const float4*)o;
    *(u16x4*)(xb + idx) = ob;
}

// scatter helpers: (B*S, D)-indexed value -> head-split layouts
DEV void scat_sd(u16* dst, int mm, int col, float v) {   // (B,NH,S,DH)
    dst[(long)((mm >> 9) * NHEAD + (col >> 6)) * HD + (long)(mm & 511) * DHEAD + (col & 63)] = f2bf(v);
}
DEV void scat_ds(u16* dst, int mm, int col, float v) {   // (B,NH,DH,S)
    dst[(long)((mm >> 9) * NHEAD + (col >> 6)) * HD + (long)(col & 63) * SEQ + (mm & 511)] = f2bf(v);
}

// ---------------------------------------------------------------------------
// m97-structure GEMM: C = A @ Bt^T + bias. A: MxK bf16, Bt: NxK bf16.
// BM x BN tile, BK=32, 4 waves, global_load_lds width-16 into linear LDS,
// double-buffered, one barrier per K-step. 1D grid + bijective XCD swizzle.
// EPI: 0=f32 (ldc), 1=bf16+relu (ldc), 2=Q scatter, 3=KV scatter, 4=QKV scatter
// ---------------------------------------------------------------------------
template <int BM, int BN, int EPI>
__global__ __launch_bounds__(256) void gemm_glds(const u16* __restrict__ A, const u16* __restrict__ Bt,
                                                 void* __restrict__ C0, void* __restrict__ C1, void* __restrict__ C2,
                                                 const float* __restrict__ bias, int K, int ldc, int gx)
{
    constexpr int NCHA = BM / 16;        // A chunks of 16 rows
    constexpr int NCH  = NCHA + BN / 16; // total chunks per buffer
    constexpr int MI   = BM / 32;        // M fragments per wave
    constexpr int NI   = BN / 32;        // N fragments per wave
    __shared__ __align__(16) u16 lds[2][NCH * 512];

    const int tid = threadIdx.x, lane = tid & 63, wid = tid >> 6;
    const int nwg = gridDim.x, bid = blockIdx.x;
    const int wg = (bid & 7) * (nwg >> 3) + (bid >> 3);     // XCD-chunk swizzle
    const int m0 = (wg / gx) * BM, n0 = (wg % gx) * BN;
    const int wr = (wid >> 1) * (BM / 2), wc = (wid & 1) * (BN / 2);
    const int fr = lane & 15, fq = lane >> 4, kg = fq * 8;
    const int srow = lane >> 2, scol = (lane & 3) * 8;      // staging lane map

    f32x4 acc[MI][NI] = {};

    auto stage = [&](int buf, int k0) {
        for (int c = wid; c < NCH; c += 4) {
            if (c < NCHA) gl_lds16(A  + (long)(m0 + c * 16 + srow) * K + k0 + scol, &lds[buf][c * 512]);
            else          gl_lds16(Bt + (long)(n0 + (c - NCHA) * 16 + srow) * K + k0 + scol, &lds[buf][c * 512]);
        }
    };

    const int nt = K >> 5;
    stage(0, 0);
    __syncthreads();                        // drains vmcnt(0): buf0 ready
    int cur = 0;
    for (int t = 0; t < nt; ++t) {
        if (t + 1 < nt) stage(cur ^ 1, (t + 1) << 5);
        bf16x8 af[MI], bfv[NI];
        #pragma unroll
        for (int mi = 0; mi < MI; ++mi)
            af[mi] = *(const bf16x8*)&lds[cur][(wr + mi * 16 + fr) * 32 + kg];
        #pragma unroll
        for (int ni = 0; ni < NI; ++ni)
            bfv[ni] = *(const bf16x8*)&lds[cur][BM * 32 + (wc + ni * 16 + fr) * 32 + kg];
        #pragma unroll
        for (int mi = 0; mi < MI; ++mi)
            #pragma unroll
            for (int ni = 0; ni < NI; ++ni)
                acc[mi][ni] = __builtin_amdgcn_mfma_f32_16x16x32_bf16(af[mi], bfv[ni], acc[mi][ni], 0, 0, 0);
        __syncthreads();
        cur ^= 1;
    }

    #pragma unroll
    for (int mi = 0; mi < MI; ++mi)
    #pragma unroll
    for (int ni = 0; ni < NI; ++ni)
    #pragma unroll
    for (int rr = 0; rr < 4; ++rr) {
        int mm = m0 + wr + mi * 16 + fq * 4 + rr;
        int nn = n0 + wc + ni * 16 + fr;
        float v = acc[mi][ni][rr] + bias[nn];
        if (EPI == 0) {
            ((float*)C0)[(long)mm * ldc + nn] = v;
        } else if (EPI == 1) {
            ((u16*)C0)[(long)mm * ldc + nn] = f2bf(fmaxf(v, 0.f));
        } else if (EPI == 2) {
            scat_sd((u16*)C0, mm, nn, v);
        } else if (EPI == 3) {
            if (nn < 512) scat_sd((u16*)C1, mm, nn, v);
            else          scat_ds((u16*)C2, mm, nn - 512, v);
        } else {            // QKV
            int which = nn >> 9, col = nn & 511;
            if (which == 0)      scat_sd((u16*)C0, mm, col, v);
            else if (which == 1) scat_sd((u16*)C1, mm, col, v);
            else                 scat_ds((u16*)C2, mm, col, v);
        }
    }
}

// ---------------------------------------------------------------------------
// Flash attention: block = one (head, 64 q-rows). 4 waves x 16 rows.
// qh,kh: per-head S x DH row-major; vT: per-head DH x S; ctx: (B,S,NH*DH).
// KV tiles of 128, double-buffered LDS (K 16KB, V^T 16KB each buf).
// Online softmax in C-layout registers; P re-layout via swizzled per-wave LDS.
// ---------------------------------------------------------------------------
template <bool CAUSAL>
__global__ __launch_bounds__(256) void flash_attn(const u16* __restrict__ qh, const u16* __restrict__ kh,
                                                  const u16* __restrict__ vT, u16* __restrict__ ctx)
{
    constexpr int KVB = 128;
    __shared__ __align__(16) u16 Kl[2][KVB * 64];    // kv x dh
    __shared__ __align__(16) u16 Vl[2][64 * KVB];    // dh x kv (V^T tile)
    __shared__ __align__(16) u16 Pl[4][16 * KVB];    // per-wave P, XOR-swizzled
    const int lane = threadIdx.x & 63, wid = threadIdx.x >> 6;
    const int head = blockIdx.x >> 3, qt = blockIdx.x & 7;
    const int q0 = qt * 64;
    const long hb = (long)head * HD;
    const int fr = lane & 15, fq = lane >> 4;

    // Q fragments: wave's rows q0+wid*16+fr, 2 k-frags over DH=64
    bf16x8 qf[2];
    #pragma unroll
    for (int kf = 0; kf < 2; ++kf)
        qf[kf] = *(const bf16x8*)(qh + hb + (long)(q0 + wid * 16 + fr) * 64 + kf * 32 + fq * 8);

    const int nt = CAUSAL ? (q0 >> 7) + 1 : SEQ / KVB;

    auto stage = [&](int buf, int t) {
        const long kv0 = (long)t * KVB;
        for (int c = wid; c < 16; c += 4)   // K: 128x64, 8 rows/chunk
            gl_lds16(kh + hb + (kv0 + c * 8 + (lane >> 3)) * 64 + (lane & 7) * 8, &Kl[buf][c * 512]);
        for (int c = wid; c < 16; c += 4)   // V^T: 64x128, 4 rows/chunk
            gl_lds16(vT + hb + (long)(c * 4 + (lane >> 4)) * SEQ + kv0 + (lane & 15) * 8, &Vl[buf][c * 512]);
    };

    float m[4], l[4];
    #pragma unroll
    for (int r = 0; r < 4; ++r) { m[r] = -3.0e38f; l[r] = 0.f; }
    f32x4 ao[4] = {};                       // O accum: rows fq*4+rr, dh col nf*16+fr

    stage(0, 0);
    __syncthreads();
    int cur = 0;
    for (int t = 0; t < nt; ++t) {
        if (t + 1 < nt) stage(cur ^ 1, t + 1);
        // ---- S = Q @ K^T (scaled) ----
        f32x4 as[8] = {};
        #pragma unroll
        for (int nf = 0; nf < 8; ++nf)
            #pragma unroll
            for (int kf = 0; kf < 2; ++kf) {
                bf16x8 kfr = *(const bf16x8*)&Kl[cur][(nf * 16 + fr) * 64 + kf * 32 + fq * 8];
                as[nf] = __builtin_amdgcn_mfma_f32_16x16x32_bf16(qf[kf], kfr, as[nf], 0, 0, 0);
            }
        const int kv0 = t * KVB;
        const int qrow = q0 + wid * 16 + fq * 4;          // + rr
        #pragma unroll
        for (int nf = 0; nf < 8; ++nf)
            #pragma unroll
            for (int rr = 0; rr < 4; ++rr) {
                float s = as[nf][rr] * 0.125f;            // 1/sqrt(64)
                if (CAUSAL && (kv0 + nf * 16 + fr > qrow + rr)) s = -3.0e38f;
                as[nf][rr] = s;
            }
        // ---- online softmax (rows owned per-lane: rr; reduce over fr lanes) ----
        float p_scale[4];
        #pragma unroll
        for (int rr = 0; rr < 4; ++rr) {
            float mx = as[0][rr];
            #pragma unroll
            for (int nf = 1; nf < 8; ++nf) mx = fmaxf(mx, as[nf][rr]);
            #pragma unroll
            for (int o = 1; o < 16; o <<= 1) mx = fmaxf(mx, __shfl_xor(mx, o, 64));
            float mnew = fmaxf(m[rr], mx);
            p_scale[rr] = __expf(m[rr] - mnew);
            m[rr] = mnew;
        }
        float rsum[4] = {0.f, 0.f, 0.f, 0.f};
        u16* pw = &Pl[wid][0];
        #pragma unroll
        for (int nf = 0; nf < 8; ++nf)
            #pragma unroll
            for (int rr = 0; rr < 4; ++rr) {
                float p = __expf(as[nf][rr] - m[rr]);
                rsum[rr] += p;
                int row = fq * 4 + rr;
                int byte = (row * 256 + (nf * 16 + fr) * 2) ^ ((row & 7) << 4);
                *(u16*)((char*)pw + byte) = f2bf(p);
            }
        #pragma unroll
        for (int rr = 0; rr < 4; ++rr) {
            #pragma unroll
            for (int o = 1; o < 16; o <<= 1) rsum[rr] += __shfl_xor(rsum[rr], o, 64);
            l[rr] = l[rr] * p_scale[rr] + rsum[rr];
        }
        #pragma unroll
        for (int nf = 0; nf < 4; ++nf)
            #pragma unroll
            for (int rr = 0; rr < 4; ++rr) ao[nf][rr] *= p_scale[rr];
        // ---- O += P @ V  (A = P via swizzled LDS, B = V^T) ----
        #pragma unroll
        for (int kf = 0; kf < 4; ++kf) {
            int byte = (fr * 256 + kf * 64 + fq * 16) ^ ((fr & 7) << 4);
            bf16x8 pa = *(const bf16x8*)((const char*)pw + byte);
            #pragma unroll
            for (int nf = 0; nf < 4; ++nf) {
                bf16x8 vf = *(const bf16x8*)&Vl[cur][(nf * 16 + fr) * KVB + kf * 32 + fq * 8];
                ao[nf] = __builtin_amdgcn_mfma_f32_16x16x32_bf16(pa, vf, ao[nf], 0, 0, 0);
            }
        }
        __syncthreads();
        cur ^= 1;
    }
    const int b = head >> 3, h = head & 7;
    #pragma unroll
    for (int nf = 0; nf < 4; ++nf)
        #pragma unroll
        for (int rr = 0; rr < 4; ++rr) {
            int qq = q0 + wid * 16 + fq * 4 + rr;
            ctx[((long)(b * SEQ + qq)) * DIM + h * 64 + nf * 16 + fr] = f2bf(ao[nf][rr] / l[rr]);
        }
}

// ---------------------------------------------------------------------------
// x = LayerNorm(x + y) * g + be;  writes f32 (xo) and bf16 (xb).
// ---------------------------------------------------------------------------
__global__ __launch_bounds__(256) void add_ln(const float* x, const float* __restrict__ y,
                                              float* xo, u16* __restrict__ xb,
                                              const float* __restrict__ g, const float* __restrict__ be)
{
    int row = blockIdx.x * 4 + (threadIdx.x >> 6);
    int lane = threadIdx.x & 63;
    long off = (long)row * DIM + lane * 8;
    float v[8];
    {
        float4 a0 = *(const float4*)(x + off);
        float4 a1 = *(const float4*)(x + off + 4);
        float4 b0 = *(const float4*)(y + off);
        float4 b1 = *(const float4*)(y + off + 4);
        v[0] = a0.x + b0.x; v[1] = a0.y + b0.y; v[2] = a0.z + b0.z; v[3] = a0.w + b0.w;
        v[4] = a1.x + b1.x; v[5] = a1.y + b1.y; v[6] = a1.z + b1.z; v[7] = a1.w + b1.w;
    }
    float sum = 0.f;
    #pragma unroll
    for (int j = 0; j < 8; ++j) sum += v[j];
    #pragma unroll
    for (int o = 32; o; o >>= 1) sum += __shfl_xor(sum, o, 64);
    float mean = sum * (1.0f / DIM);
    float vs = 0.f;
    #pragma unroll
    for (int j = 0; j < 8; ++j) { float d = v[j] - mean; vs += d * d; }
    #pragma unroll
    for (int o = 32; o; o >>= 1) vs += __shfl_xor(vs, o, 64);
    float rstd = rsqrtf(vs * (1.0f / DIM) + 1e-5f);
    float outv[8]; u16x8 ob;
    #pragma unroll
    for (int j = 0; j < 8; ++j) {
        int col = lane * 8 + j;
        float r = (v[j] - mean) * rstd * g[col] + be[col];
        outv[j] = r; ob[j] = f2bf(r);
    }
    *(float4*)(xo + off)     = *(const float4*)&outv[0];
    *(float4*)(xo + off + 4) = *(const float4*)&outv[4];
    *(u16x8*)(xb + off) = ob;
}

// ---------------------------------------------------------------------------
extern "C" void kernel_launch(void* const* d_in, const int* in_sizes, int n_in,
                              void* d_out, int out_size, void* d_ws, size_t ws_size,
                              hipStream_t stream)
{
    const int*   targets = (const int*)  d_in[0];
    const float* memory  = (const float*)d_in[1];
    // d_in[2]=trg_mask (causal, analytic), d_in[3]=memory_mask (all false) -> unread
    const float* emb     = (const float*)d_in[4];
    const float* Wg[8]; for (int i = 0; i < 8; ++i) Wg[i] = (const float*)d_in[5 + i];
    const float* bg[8]; for (int i = 0; i < 8; ++i) bg[i] = (const float*)d_in[13 + i];
    const float* W1  = (const float*)d_in[21];
    const float* b1  = (const float*)d_in[22];
    const float* W2  = (const float*)d_in[23];
    const float* b2  = (const float*)d_in[24];
    const float* g1  = (const float*)d_in[25];
    const float* g2  = (const float*)d_in[26];
    const float* g3  = (const float*)d_in[27];
    const float* be1 = (const float*)d_in[28];
    const float* be2 = (const float*)d_in[29];
    const float* be3 = (const float*)d_in[30];

    char* w = (char*)d_ws;
    auto take = [&](size_t n) -> char* { char* p = w; w += (n + 255) & ~(size_t)255; return p; };
    u16*   wqkvT = (u16*)take((size_t)NLAY * 3 * DIM * DIM * 2);   // [L][1536][512]
    u16*   wkvcT = (u16*)take((size_t)NLAY * 2 * DIM * DIM * 2);   // [L][1024][512]
    u16*   wqcT  = (u16*)take((size_t)NLAY * DIM * DIM * 2);
    u16*   woT   = (u16*)take((size_t)NLAY * DIM * DIM * 2);
    u16*   wocT  = (u16*)take((size_t)NLAY * DIM * DIM * 2);
    u16*   w1T   = (u16*)take((size_t)NLAY * DIM * DFFN * 2);      // [L][2048][512]
    u16*   w2T   = (u16*)take((size_t)NLAY * DIM * DFFN * 2);      // [L][512][2048]
    float* bqkv  = (float*)take((size_t)NLAY * 3 * DIM * 4);
    float* bkvc  = (float*)take((size_t)NLAY * 2 * DIM * 4);
    float* x     = (float*)take((size_t)MROWS * DIM * 4);
    float* y     = (float*)take((size_t)MROWS * DIM * 4);
    u16*   xb    = (u16*)  take((size_t)MROWS * DIM * 2);
    u16*   memb  = (u16*)  take((size_t)MROWS * DIM * 2);
    u16*   qh    = (u16*)  take((size_t)MROWS * DIM * 2);
    u16*   kh    = (u16*)  take((size_t)MROWS * DIM * 2);
    u16*   vT    = (u16*)  take((size_t)MROWS * DIM * 2);
    u16*   ctx   = (u16*)  take((size_t)MROWS * DIM * 2);
    u16*   h1    = (u16*)  take((size_t)MROWS * DFFN * 2);         // FFN hidden

    const long SQ = (long)DIM * DIM;  // 262144
    transpose_w<<<dim3(16, 16, NLAY), 256, 0, stream>>>(Wg[0], wqkvT,          DIM, DIM, 3 * SQ);
    transpose_w<<<dim3(16, 16, NLAY), 256, 0, stream>>>(Wg[1], wqkvT + SQ,     DIM, DIM, 3 * SQ);
    transpose_w<<<dim3(16, 16, NLAY), 256, 0, stream>>>(Wg[2], wqkvT + 2 * SQ, DIM, DIM, 3 * SQ);
    transpose_w<<<dim3(16, 16, NLAY), 256, 0, stream>>>(Wg[3], woT,            DIM, DIM, SQ);
    transpose_w<<<dim3(16, 16, NLAY), 256, 0, stream>>>(Wg[4], wqcT,           DIM, DIM, SQ);
    transpose_w<<<dim3(16, 16, NLAY), 256, 0, stream>>>(Wg[5], wkvcT,          DIM, DIM, 2 * SQ);
    transpose_w<<<dim3(16, 16, NLAY), 256, 0, stream>>>(Wg[6], wkvcT + SQ,     DIM, DIM, 2 * SQ);
    transpose_w<<<dim3(16, 16, NLAY), 256, 0, stream>>>(Wg[7], wocT,           DIM, DIM, SQ);
    transpose_w<<<dim3(64, 16, NLAY), 256, 0, stream>>>(W1, w1T, DIM, DFFN, (long)DIM * DFFN);
    transpose_w<<<dim3(16, 64, NLAY), 256, 0, stream>>>(W2, w2T, DFFN, DIM, (long)DIM * DFFN);
    concat_bias<<<NLAY * 3 * DIM / 256, 256, 0, stream>>>(bg[0], bg[1], bg[2], bqkv, 3);
    concat_bias<<<NLAY * 2 * DIM / 256, 256, 0, stream>>>(bg[5], bg[6], nullptr, bkvc, 2);
    conv_f32_bf16<<<2048, 256, 0, stream>>>(memory, memb);
    embed_pe<<<2048, 256, 0, stream>>>(targets, emb, x, xb);

    for (int i = 0; i < NLAY; ++i) {
        const u16 *wqkv = wqkvT + (long)i * 3 * SQ, *wkvc = wkvcT + (long)i * 2 * SQ;
        const u16 *wqc = wqcT + (long)i * SQ, *wo = woT + (long)i * SQ, *woc = wocT + (long)i * SQ;
        const u16 *w1t = w1T + (long)i * DIM * DFFN, *w2t = w2T + (long)i * DIM * DFFN;
        const float *bo = bg[3] + i * DIM, *bqc = bg[4] + i * DIM, *boc = bg[7] + i * DIM;

        // ---- self attention (causal) ----
        gemm_glds<64, 128, 4><<<768, 256, 0, stream>>>(xb, wqkv, qh, kh, vT, bqkv + i * 3 * DIM, DIM, 0, 12);
        flash_attn<true><<<BATCH * NHEAD * (SEQ / 64), 256, 0, stream>>>(qh, kh, vT, ctx);
        gemm_glds<64, 64, 0><<<512, 256, 0, stream>>>(ctx, wo, y, nullptr, nullptr, bo, DIM, DIM, 8);
        add_ln<<<MROWS / 4, 256, 0, stream>>>(x, y, x, xb, g1 + i * DIM, be1 + i * DIM);

        // ---- cross attention (no mask) ----
        gemm_glds<64, 64, 2><<<512, 256, 0, stream>>>(xb, wqc, qh, nullptr, nullptr, bqc, DIM, 0, 8);
        gemm_glds<64, 128, 3><<<512, 256, 0, stream>>>(memb, wkvc, nullptr, kh, vT, bkvc + i * 2 * DIM, DIM, 0, 8);
        flash_attn<false><<<BATCH * NHEAD * (SEQ / 64), 256, 0, stream>>>(qh, kh, vT, ctx);
        gemm_glds<64, 64, 0><<<512, 256, 0, stream>>>(ctx, woc, y, nullptr, nullptr, boc, DIM, DIM, 8);
        add_ln<<<MROWS / 4, 256, 0, stream>>>(x, y, x, xb, g2 + i * DIM, be2 + i * DIM);

        // ---- FFN ----
        gemm_glds<64, 128, 1><<<1024, 256, 0, stream>>>(xb, w1t, h1, nullptr, nullptr, b1 + i * DFFN, DIM, DFFN, 16);
        gemm_glds<64, 64, 0><<<512, 256, 0, stream>>>(h1, w2t, y, nullptr, nullptr, b2 + i * DIM, DFFN, DIM, 8);
        float* xo = (i == NLAY - 1) ? (float*)d_out : x;
        add_ln<<<MROWS / 4, 256, 0, stream>>>(x, y, xo, xb, g3 + i * DIM, be3 + i * DIM);
    }
}

// Round 5
// 978.828 us; speedup vs baseline: 1.6647x; 1.2385x over previous
//
#include <hip/hip_runtime.h>

typedef unsigned short u16;
typedef unsigned int   u32;
typedef __attribute__((ext_vector_type(4))) u16   u16x4;
typedef __attribute__((ext_vector_type(8))) u16   u16x8;
typedef __attribute__((ext_vector_type(8))) __bf16 bf16x8;
typedef __attribute__((ext_vector_type(4))) float f32x4;

#define DEV static __device__ __forceinline__

constexpr int DIM = 512, NHEAD = 8, DHEAD = 64, DFFN = 2048, NLAY = 6, SEQ = 512, BATCH = 8;
constexpr int MROWS = BATCH * SEQ;            // 4096 token rows
constexpr long HD = (long)SEQ * DHEAD;        // 32768 per-head q/k/v block
constexpr long SQ = (long)DIM * DIM;          // 262144

DEV float bf2f(u16 u) { union { u32 i; float f; } x; x.i = (u32)u << 16; return x.f; }
DEV u16 f2bf(float f) { union { float f; u32 i; } x; x.f = f; u32 r = x.i + 0x7fffu + ((x.i >> 16) & 1u); return (u16)(r >> 16); }

DEV void gl_lds16(const u16* g, u16* l) {
    __builtin_amdgcn_global_load_lds((const __attribute__((address_space(1))) u32*)(const void*)g,
                                     (__attribute__((address_space(3))) u32*)(void*)l, 16, 0, 0);
}

// ---------------------------------------------------------------------------
// Merged transpose for the 8 square (512x512 per layer) weights.
// out[which][layer*ls + n*512 + k] = bf16(in[which][layer*SQ + k*512 + n])
// ---------------------------------------------------------------------------
struct TP { const float* in[8]; u16* out[8]; long ls[8]; };

__global__ __launch_bounds__(256) void transpose8(TP p)
{
    __shared__ u16 t[32][33];
    int z = blockIdx.z, which = z / NLAY, l = z % NLAY;
    const float* in = p.in[which] + (long)l * SQ;
    u16* out = p.out[which] + (long)l * p.ls[which];
    int k0 = blockIdx.y * 32, n0 = blockIdx.x * 32;
    int tx = threadIdx.x & 31, ty = threadIdx.x >> 5;
    #pragma unroll
    for (int i = ty; i < 32; i += 8) t[i][tx] = f2bf(in[(long)(k0 + i) * 512 + n0 + tx]);
    __syncthreads();
    #pragma unroll
    for (int i = ty; i < 32; i += 8) out[(long)(n0 + i) * 512 + k0 + tx] = t[tx][i];
}

// generic transpose (for W1/W2): out[z*outLS + n*K + k] = bf16(in[z*K*N + k*N + n])
__global__ __launch_bounds__(256) void transpose_w(const float* __restrict__ in, u16* __restrict__ out,
                                                   int K, int N, long outLS)
{
    __shared__ u16 t[32][33];
    long bi = (long)blockIdx.z * K * N, bo = (long)blockIdx.z * outLS;
    int k0 = blockIdx.y * 32, n0 = blockIdx.x * 32;
    int tx = threadIdx.x & 31, ty = threadIdx.x >> 5;
    #pragma unroll
    for (int i = ty; i < 32; i += 8) t[i][tx] = f2bf(in[bi + (long)(k0 + i) * N + n0 + tx]);
    __syncthreads();
    #pragma unroll
    for (int i = ty; i < 32; i += 8) out[bo + (long)(n0 + i) * K + k0 + tx] = t[tx][i];
}

// concat per-layer bias vectors (each NLAY x 512) into [NLAY][nsrc*512]
__global__ __launch_bounds__(256) void concat_bias(const float* __restrict__ a, const float* __restrict__ b,
                                                   const float* __restrict__ c, float* __restrict__ out, int nsrc)
{
    int i = blockIdx.x * 256 + threadIdx.x;
    int col = i & 511, j = (i >> 9) % nsrc, l = i / (nsrc * 512);
    const float* s = (j == 0) ? a : (j == 1) ? b : c;
    out[i] = s[l * 512 + col];
}

__global__ __launch_bounds__(256) void conv_f32_bf16(const float* __restrict__ in, u16* __restrict__ out)
{
    long i = ((long)blockIdx.x * 256 + threadIdx.x) * 4;
    float4 v = *(const float4*)(in + i);
    u16x4 o; o.x = f2bf(v.x); o.y = f2bf(v.y); o.z = f2bf(v.z); o.w = f2bf(v.w);
    *(u16x4*)(out + i) = o;
}

// ---------------------------------------------------------------------------
// Embedding * sqrt(D) + sinusoidal positional encoding -> x (f32) and xb (bf16)
// ---------------------------------------------------------------------------
__global__ __launch_bounds__(256) void embed_pe(const int* __restrict__ targets, const float* __restrict__ emb,
                                                float* __restrict__ x, u16* __restrict__ xb)
{
    int t4 = (blockIdx.x * 256 + threadIdx.x) * 4;
    int d = t4 & (DIM - 1);
    int s = (t4 >> 9) & (SEQ - 1);
    int b = t4 >> 18;
    int tok = targets[s * BATCH + b];
    float4 e = *(const float4*)(emb + (long)tok * DIM + d);
    float o[4]; u16x4 ob;
    const float ef[4] = { e.x, e.y, e.z, e.w };
    #pragma unroll
    for (int j = 0; j < 4; ++j) {
        int dd = d + j;
        float div = expf((float)(dd & ~1) * -0.017988946039016f);  // -ln(10000)/512
        float ang = (float)s * div;
        float pe = (dd & 1) ? cosf(ang) : sinf(ang);
        float val = ef[j] * 22.627416997969522f + pe;              // sqrt(512)
        o[j] = val; ob[j] = f2bf(val);
    }
    long idx = ((long)b * SEQ + s) * DIM + d;
    *(float4*)(x + idx) = *(const float4*)o;
    *(u16x4*)(xb + idx) = ob;
}

// scatter helpers: (B*S, D)-indexed value -> head-split layouts
DEV void scat_sd(u16* dst, int mm, int col, float v) {   // (B,NH,S,DH)
    dst[(long)((mm >> 9) * NHEAD + (col >> 6)) * HD + (long)(mm & 511) * DHEAD + (col & 63)] = f2bf(v);
}
DEV void scat_ds(u16* dst, int mm, int col, float v) {   // (B,NH,DH,S)
    dst[(long)((mm >> 9) * NHEAD + (col >> 6)) * HD + (long)(col & 63) * SEQ + (mm & 511)] = f2bf(v);
}

// ---------------------------------------------------------------------------
// GEMM: C = A @ Bt^T + bias.  BM=64, BK=64, 4 waves (wave tile 32 x BN/2).
// LDS rows are 64 elems (128B); both-sides XOR swizzle keeps global_load_lds
// linear while making ds_read_b128 bank-conflict-free:
//   stage: lane source col = ((lane&7)^(lane>>3))*8 within the 8-row chunk
//   read : in-row byte offset ^= (fr&7)<<4
// A pointer selected per block by n0 < aSplit (enables fused cross Q|K|V).
// 1D grid + bijective XCD swizzle (grid % 8 == 0).
// EPI: 0=bf16 plain (ldc), 1=bf16+relu (ldc), 4=QKV head-split scatter
// ---------------------------------------------------------------------------
template <int BN, int EPI>
__global__ __launch_bounds__(256) void gemm64(const u16* __restrict__ A0, const u16* __restrict__ A1,
                                              const u16* __restrict__ Bt,
                                              void* __restrict__ C0, void* __restrict__ C1, void* __restrict__ C2,
                                              const float* __restrict__ bias, int K, int ldc, int gx, int aSplit)
{
    constexpr int NCH = (64 + BN) / 8;   // 8-row chunks (A then B)
    constexpr int NI  = BN / 32;         // N frags per wave per k-slice
    __shared__ __align__(16) u16 lds[2][NCH * 512];

    const int tid = threadIdx.x, lane = tid & 63, wid = tid >> 6;
    const int nwg = gridDim.x, bid = blockIdx.x;
    const int wg = (bid & 7) * (nwg >> 3) + (bid >> 3);     // XCD-chunk swizzle
    const int m0 = (wg / gx) * 64, n0 = (wg % gx) * BN;
    const u16* A = (n0 < aSplit) ? A0 : A1;
    const int wr = (wid >> 1) * 32, wc = (wid & 1) * (BN / 2);
    const int fr = lane & 15, fq = lane >> 4;
    const int srow = lane >> 3;                              // 0..7 row in chunk
    const int scol = ((lane & 7) ^ srow) * 8;                // pre-swizzled source col

    f32x4 acc[2][NI] = {};

    auto stage = [&](int buf, int k0) {
        #pragma unroll
        for (int c = wid; c < 8; c += 4)
            gl_lds16(A + (long)(m0 + c * 8 + srow) * K + k0 + scol, &lds[buf][c * 512]);
        #pragma unroll
        for (int c = 8 + wid; c < NCH; c += 4)
            gl_lds16(Bt + (long)(n0 + (c - 8) * 8 + srow) * K + k0 + scol, &lds[buf][c * 512]);
    };

    const int nt = K >> 6;
    stage(0, 0);
    __syncthreads();                        // drains vmcnt(0): buf0 ready
    int cur = 0;
    const int swz = (fr & 7) << 4;
    for (int t = 0; t < nt; ++t) {
        if (t + 1 < nt) stage(cur ^ 1, (t + 1) << 6);
        const char* lb = (const char*)&lds[cur][0];
        bf16x8 a[2][2], b[NI][2];
        #pragma unroll
        for (int mi = 0; mi < 2; ++mi)
            #pragma unroll
            for (int kk = 0; kk < 2; ++kk)
                a[mi][kk] = *(const bf16x8*)(lb + (wr + mi * 16 + fr) * 128 + ((kk * 64 + fq * 16) ^ swz));
        #pragma unroll
        for (int ni = 0; ni < NI; ++ni)
            #pragma unroll
            for (int kk = 0; kk < 2; ++kk)
                b[ni][kk] = *(const bf16x8*)(lb + (64 + wc + ni * 16 + fr) * 128 + ((kk * 64 + fq * 16) ^ swz));
        #pragma unroll
        for (int kk = 0; kk < 2; ++kk)
            #pragma unroll
            for (int mi = 0; mi < 2; ++mi)
                #pragma unroll
                for (int ni = 0; ni < NI; ++ni)
                    acc[mi][ni] = __builtin_amdgcn_mfma_f32_16x16x32_bf16(a[mi][kk], b[ni][kk], acc[mi][ni], 0, 0, 0);
        __syncthreads();
        cur ^= 1;
    }

    #pragma unroll
    for (int mi = 0; mi < 2; ++mi)
    #pragma unroll
    for (int ni = 0; ni < NI; ++ni)
    #pragma unroll
    for (int rr = 0; rr < 4; ++rr) {
        int mm = m0 + wr + mi * 16 + fq * 4 + rr;
        int nn = n0 + wc + ni * 16 + fr;
        float v = acc[mi][ni][rr] + bias[nn];
        if (EPI == 0) {
            ((u16*)C0)[(long)mm * ldc + nn] = f2bf(v);
        } else if (EPI == 1) {
            ((u16*)C0)[(long)mm * ldc + nn] = f2bf(fmaxf(v, 0.f));
        } else {            // QKV head-split
            int which = nn >> 9, col = nn & 511;
            if (which == 0)      scat_sd((u16*)C0, mm, col, v);
            else if (which == 1) scat_sd((u16*)C1, mm, col, v);
            else                 scat_ds((u16*)C2, mm, col, v);
        }
    }
}

// ---------------------------------------------------------------------------
// Flash attention: block = one (head, 64 q-rows). 4 waves x 16 rows.
// qh,kh: per-head S x DH row-major; vT: per-head DH x S; ctx: (B,S,NH*DH).
// KV tiles of 128, double-buffered LDS. Online softmax in C-layout registers;
// P re-layout via swizzled per-wave LDS slab.
// ---------------------------------------------------------------------------
template <bool CAUSAL>
__global__ __launch_bounds__(256) void flash_attn(const u16* __restrict__ qh, const u16* __restrict__ kh,
                                                  const u16* __restrict__ vT, u16* __restrict__ ctx)
{
    constexpr int KVB = 128;
    __shared__ __align__(16) u16 Kl[2][KVB * 64];    // kv x dh
    __shared__ __align__(16) u16 Vl[2][64 * KVB];    // dh x kv (V^T tile)
    __shared__ __align__(16) u16 Pl[4][16 * KVB];    // per-wave P, XOR-swizzled
    const int lane = threadIdx.x & 63, wid = threadIdx.x >> 6;
    const int head = blockIdx.x >> 3, qt = blockIdx.x & 7;
    const int q0 = qt * 64;
    const long hb = (long)head * HD;
    const int fr = lane & 15, fq = lane >> 4;

    bf16x8 qf[2];
    #pragma unroll
    for (int kf = 0; kf < 2; ++kf)
        qf[kf] = *(const bf16x8*)(qh + hb + (long)(q0 + wid * 16 + fr) * 64 + kf * 32 + fq * 8);

    const int nt = CAUSAL ? (q0 >> 7) + 1 : SEQ / KVB;

    auto stage = [&](int buf, int t) {
        const long kv0 = (long)t * KVB;
        for (int c = wid; c < 16; c += 4)   // K: 128x64
            gl_lds16(kh + hb + (kv0 + c * 8 + (lane >> 3)) * 64 + (lane & 7) * 8, &Kl[buf][c * 512]);
        for (int c = wid; c < 16; c += 4)   // V^T: 64x128
            gl_lds16(vT + hb + (long)(c * 4 + (lane >> 4)) * SEQ + kv0 + (lane & 15) * 8, &Vl[buf][c * 512]);
    };

    float m[4], l[4];
    #pragma unroll
    for (int r = 0; r < 4; ++r) { m[r] = -3.0e38f; l[r] = 0.f; }
    f32x4 ao[4] = {};

    stage(0, 0);
    __syncthreads();
    int cur = 0;
    for (int t = 0; t < nt; ++t) {
        if (t + 1 < nt) stage(cur ^ 1, t + 1);
        f32x4 as[8] = {};
        #pragma unroll
        for (int nf = 0; nf < 8; ++nf)
            #pragma unroll
            for (int kf = 0; kf < 2; ++kf) {
                bf16x8 kfr = *(const bf16x8*)&Kl[cur][(nf * 16 + fr) * 64 + kf * 32 + fq * 8];
                as[nf] = __builtin_amdgcn_mfma_f32_16x16x32_bf16(qf[kf], kfr, as[nf], 0, 0, 0);
            }
        const int kv0 = t * KVB;
        const int qrow = q0 + wid * 16 + fq * 4;
        #pragma unroll
        for (int nf = 0; nf < 8; ++nf)
            #pragma unroll
            for (int rr = 0; rr < 4; ++rr) {
                float s = as[nf][rr] * 0.125f;
                if (CAUSAL && (kv0 + nf * 16 + fr > qrow + rr)) s = -3.0e38f;
                as[nf][rr] = s;
            }
        float p_scale[4];
        #pragma unroll
        for (int rr = 0; rr < 4; ++rr) {
            float mx = as[0][rr];
            #pragma unroll
            for (int nf = 1; nf < 8; ++nf) mx = fmaxf(mx, as[nf][rr]);
            #pragma unroll
            for (int o = 1; o < 16; o <<= 1) mx = fmaxf(mx, __shfl_xor(mx, o, 64));
            float mnew = fmaxf(m[rr], mx);
            p_scale[rr] = __expf(m[rr] - mnew);
            m[rr] = mnew;
        }
        float rsum[4] = {0.f, 0.f, 0.f, 0.f};
        u16* pw = &Pl[wid][0];
        #pragma unroll
        for (int nf = 0; nf < 8; ++nf)
            #pragma unroll
            for (int rr = 0; rr < 4; ++rr) {
                float p = __expf(as[nf][rr] - m[rr]);
                rsum[rr] += p;
                int row = fq * 4 + rr;
                int byte = (row * 256 + (nf * 16 + fr) * 2) ^ ((row & 7) << 4);
                *(u16*)((char*)pw + byte) = f2bf(p);
            }
        #pragma unroll
        for (int rr = 0; rr < 4; ++rr) {
            #pragma unroll
            for (int o = 1; o < 16; o <<= 1) rsum[rr] += __shfl_xor(rsum[rr], o, 64);
            l[rr] = l[rr] * p_scale[rr] + rsum[rr];
        }
        #pragma unroll
        for (int nf = 0; nf < 4; ++nf)
            #pragma unroll
            for (int rr = 0; rr < 4; ++rr) ao[nf][rr] *= p_scale[rr];
        #pragma unroll
        for (int kf = 0; kf < 4; ++kf) {
            int byte = (fr * 256 + kf * 64 + fq * 16) ^ ((fr & 7) << 4);
            bf16x8 pa = *(const bf16x8*)((const char*)pw + byte);
            #pragma unroll
            for (int nf = 0; nf < 4; ++nf) {
                bf16x8 vf = *(const bf16x8*)&Vl[cur][(nf * 16 + fr) * KVB + kf * 32 + fq * 8];
                ao[nf] = __builtin_amdgcn_mfma_f32_16x16x32_bf16(pa, vf, ao[nf], 0, 0, 0);
            }
        }
        __syncthreads();
        cur ^= 1;
    }
    const int b = head >> 3, h = head & 7;
    #pragma unroll
    for (int nf = 0; nf < 4; ++nf)
        #pragma unroll
        for (int rr = 0; rr < 4; ++rr) {
            int qq = q0 + wid * 16 + fq * 4 + rr;
            ctx[((long)(b * SEQ + qq)) * DIM + h * 64 + nf * 16 + fr] = f2bf(ao[nf][rr] / l[rr]);
        }
}

// ---------------------------------------------------------------------------
// x = LayerNorm(x + y) * g + be;  y is bf16. Writes f32 (xo) and bf16 (xb).
// ---------------------------------------------------------------------------
__global__ __launch_bounds__(256) void add_ln(const float* x, const u16* __restrict__ y,
                                              float* xo, u16* __restrict__ xb,
                                              const float* __restrict__ g, const float* __restrict__ be)
{
    int row = blockIdx.x * 4 + (threadIdx.x >> 6);
    int lane = threadIdx.x & 63;
    long off = (long)row * DIM + lane * 8;
    float v[8];
    {
        float4 a0 = *(const float4*)(x + off);
        float4 a1 = *(const float4*)(x + off + 4);
        u16x8 yv = *(const u16x8*)(y + off);
        v[0] = a0.x + bf2f(yv[0]); v[1] = a0.y + bf2f(yv[1]);
        v[2] = a0.z + bf2f(yv[2]); v[3] = a0.w + bf2f(yv[3]);
        v[4] = a1.x + bf2f(yv[4]); v[5] = a1.y + bf2f(yv[5]);
        v[6] = a1.z + bf2f(yv[6]); v[7] = a1.w + bf2f(yv[7]);
    }
    float sum = 0.f;
    #pragma unroll
    for (int j = 0; j < 8; ++j) sum += v[j];
    #pragma unroll
    for (int o = 32; o; o >>= 1) sum += __shfl_xor(sum, o, 64);
    float mean = sum * (1.0f / DIM);
    float vs = 0.f;
    #pragma unroll
    for (int j = 0; j < 8; ++j) { float d = v[j] - mean; vs += d * d; }
    #pragma unroll
    for (int o = 32; o; o >>= 1) vs += __shfl_xor(vs, o, 64);
    float rstd = rsqrtf(vs * (1.0f / DIM) + 1e-5f);
    float outv[8]; u16x8 ob;
    #pragma unroll
    for (int j = 0; j < 8; ++j) {
        int col = lane * 8 + j;
        float r = (v[j] - mean) * rstd * g[col] + be[col];
        outv[j] = r; ob[j] = f2bf(r);
    }
    *(float4*)(xo + off)     = *(const float4*)&outv[0];
    *(float4*)(xo + off + 4) = *(const float4*)&outv[4];
    *(u16x8*)(xb + off) = ob;
}

// ---------------------------------------------------------------------------
extern "C" void kernel_launch(void* const* d_in, const int* in_sizes, int n_in,
                              void* d_out, int out_size, void* d_ws, size_t ws_size,
                              hipStream_t stream)
{
    const int*   targets = (const int*)  d_in[0];
    const float* memory  = (const float*)d_in[1];
    // d_in[2]=trg_mask (causal, analytic), d_in[3]=memory_mask (all false) -> unread
    const float* emb     = (const float*)d_in[4];
    const float* Wg[8]; for (int i = 0; i < 8; ++i) Wg[i] = (const float*)d_in[5 + i];
    const float* bg[8]; for (int i = 0; i < 8; ++i) bg[i] = (const float*)d_in[13 + i];
    const float* W1  = (const float*)d_in[21];
    const float* b1  = (const float*)d_in[22];
    const float* W2  = (const float*)d_in[23];
    const float* b2  = (const float*)d_in[24];
    const float* g1  = (const float*)d_in[25];
    const float* g2  = (const float*)d_in[26];
    const float* g3  = (const float*)d_in[27];
    const float* be1 = (const float*)d_in[28];
    const float* be2 = (const float*)d_in[29];
    const float* be3 = (const float*)d_in[30];

    char* w = (char*)d_ws;
    auto take = [&](size_t n) -> char* { char* p = w; w += (n + 255) & ~(size_t)255; return p; };
    u16*   wqkvT = (u16*)take((size_t)NLAY * 3 * SQ * 2);   // self  [L][1536][512]
    u16*   wcatT = (u16*)take((size_t)NLAY * 3 * SQ * 2);   // cross [L][1536][512] (Wq_c|Wk_c|Wv_c)
    u16*   woT   = (u16*)take((size_t)NLAY * SQ * 2);
    u16*   wocT  = (u16*)take((size_t)NLAY * SQ * 2);
    u16*   w1T   = (u16*)take((size_t)NLAY * DIM * DFFN * 2);
    u16*   w2T   = (u16*)take((size_t)NLAY * DIM * DFFN * 2);
    float* bqkv  = (float*)take((size_t)NLAY * 3 * DIM * 4);
    float* bqkvc = (float*)take((size_t)NLAY * 3 * DIM * 4);
    float* x     = (float*)take((size_t)MROWS * DIM * 4);
    u16*   y     = (u16*)  take((size_t)MROWS * DIM * 2);
    u16*   xb    = (u16*)  take((size_t)MROWS * DIM * 2);
    u16*   memb  = (u16*)  take((size_t)MROWS * DIM * 2);
    u16*   qh    = (u16*)  take((size_t)MROWS * DIM * 2);
    u16*   kh    = (u16*)  take((size_t)MROWS * DIM * 2);
    u16*   vT    = (u16*)  take((size_t)MROWS * DIM * 2);
    u16*   ctx   = (u16*)  take((size_t)MROWS * DIM * 2);
    u16*   h1    = (u16*)  take((size_t)MROWS * DFFN * 2);

    TP tp;
    tp.in[0] = Wg[0]; tp.out[0] = wqkvT;          tp.ls[0] = 3 * SQ;
    tp.in[1] = Wg[1]; tp.out[1] = wqkvT + SQ;     tp.ls[1] = 3 * SQ;
    tp.in[2] = Wg[2]; tp.out[2] = wqkvT + 2 * SQ; tp.ls[2] = 3 * SQ;
    tp.in[3] = Wg[3]; tp.out[3] = woT;            tp.ls[3] = SQ;
    tp.in[4] = Wg[4]; tp.out[4] = wcatT;          tp.ls[4] = 3 * SQ;
    tp.in[5] = Wg[5]; tp.out[5] = wcatT + SQ;     tp.ls[5] = 3 * SQ;
    tp.in[6] = Wg[6]; tp.out[6] = wcatT + 2 * SQ; tp.ls[6] = 3 * SQ;
    tp.in[7] = Wg[7]; tp.out[7] = wocT;           tp.ls[7] = SQ;
    transpose8<<<dim3(16, 16, 8 * NLAY), 256, 0, stream>>>(tp);
    transpose_w<<<dim3(64, 16, NLAY), 256, 0, stream>>>(W1, w1T, DIM, DFFN, (long)DIM * DFFN);
    transpose_w<<<dim3(16, 64, NLAY), 256, 0, stream>>>(W2, w2T, DFFN, DIM, (long)DIM * DFFN);
    concat_bias<<<NLAY * 3 * DIM / 256, 256, 0, stream>>>(bg[0], bg[1], bg[2], bqkv, 3);
    concat_bias<<<NLAY * 3 * DIM / 256, 256, 0, stream>>>(bg[4], bg[5], bg[6], bqkvc, 3);
    conv_f32_bf16<<<2048, 256, 0, stream>>>(memory, memb);
    embed_pe<<<2048, 256, 0, stream>>>(targets, emb, x, xb);

    const int BIG = 1 << 30;
    for (int i = 0; i < NLAY; ++i) {
        const u16 *wqkv = wqkvT + (long)i * 3 * SQ, *wcat = wcatT + (long)i * 3 * SQ;
        const u16 *wo = woT + (long)i * SQ, *woc = wocT + (long)i * SQ;
        const u16 *w1t = w1T + (long)i * DIM * DFFN, *w2t = w2T + (long)i * DIM * DFFN;
        const float *bo = bg[3] + i * DIM, *boc = bg[7] + i * DIM;

        // ---- self attention (causal) ----
        gemm64<128, 4><<<768, 256, 0, stream>>>(xb, xb, wqkv, qh, kh, vT, bqkv + i * 3 * DIM, DIM, 0, 12, BIG);
        flash_attn<true><<<BATCH * NHEAD * (SEQ / 64), 256, 0, stream>>>(qh, kh, vT, ctx);
        gemm64<64, 0><<<512, 256, 0, stream>>>(ctx, ctx, wo, y, nullptr, nullptr, bo, DIM, DIM, 8, BIG);
        add_ln<<<MROWS / 4, 256, 0, stream>>>(x, y, x, xb, g1 + i * DIM, be1 + i * DIM);

        // ---- cross attention (no mask): fused Q(from xb) | K,V (from memb) ----
        gemm64<128, 4><<<768, 256, 0, stream>>>(xb, memb, wcat, qh, kh, vT, bqkvc + i * 3 * DIM, DIM, 0, 12, 512);
        flash_attn<false><<<BATCH * NHEAD * (SEQ / 64), 256, 0, stream>>>(qh, kh, vT, ctx);
        gemm64<64, 0><<<512, 256, 0, stream>>>(ctx, ctx, woc, y, nullptr, nullptr, boc, DIM, DIM, 8, BIG);
        add_ln<<<MROWS / 4, 256, 0, stream>>>(x, y, x, xb, g2 + i * DIM, be2 + i * DIM);

        // ---- FFN ----
        gemm64<128, 1><<<1024, 256, 0, stream>>>(xb, xb, w1t, h1, nullptr, nullptr, b1 + i * DFFN, DIM, DFFN, 16, BIG);
        gemm64<64, 0><<<512, 256, 0, stream>>>(h1, h1, w2t, y, nullptr, nullptr, b2 + i * DIM, DFFN, DIM, 8, BIG);
        float* xo = (i == NLAY - 1) ? (float*)d_out : x;
        add_ln<<<MROWS / 4, 256, 0, stream>>>(x, y, xo, xb, g3 + i * DIM, be3 + i * DIM);
    }
}

// Round 6
// 924.987 us; speedup vs baseline: 1.7616x; 1.0582x over previous
//
#include <hip/hip_runtime.h>

typedef unsigned short u16;
typedef unsigned int   u32;
typedef __attribute__((ext_vector_type(4))) u16   u16x4;
typedef __attribute__((ext_vector_type(8))) u16   u16x8;
typedef __attribute__((ext_vector_type(8))) __bf16 bf16x8;
typedef __attribute__((ext_vector_type(4))) float f32x4;

#define DEV static __device__ __forceinline__

constexpr int DIM = 512, NHEAD = 8, DHEAD = 64, DFFN = 2048, NLAY = 6, SEQ = 512, BATCH = 8;
constexpr int MROWS = BATCH * SEQ;            // 4096 token rows
constexpr long HD = (long)SEQ * DHEAD;        // 32768 per-head q/k/v block
constexpr long SQ = (long)DIM * DIM;          // 262144

DEV float bf2f(u16 u) { union { u32 i; float f; } x; x.i = (u32)u << 16; return x.f; }
DEV u16 f2bf(float f) { union { float f; u32 i; } x; x.f = f; u32 r = x.i + 0x7fffu + ((x.i >> 16) & 1u); return (u16)(r >> 16); }

DEV void gl_lds16(const u16* g, u16* l) {
    __builtin_amdgcn_global_load_lds((const __attribute__((address_space(1))) u32*)(const void*)g,
                                     (__attribute__((address_space(3))) u32*)(void*)l, 16, 0, 0);
}

// ---------------------------------------------------------------------------
// Merged transpose for the 8 square (512x512 per layer) weights.
// ---------------------------------------------------------------------------
struct TP { const float* in[8]; u16* out[8]; long ls[8]; };

__global__ __launch_bounds__(256) void transpose8(TP p)
{
    __shared__ u16 t[32][33];
    int z = blockIdx.z, which = z / NLAY, l = z % NLAY;
    const float* in = p.in[which] + (long)l * SQ;
    u16* out = p.out[which] + (long)l * p.ls[which];
    int k0 = blockIdx.y * 32, n0 = blockIdx.x * 32;
    int tx = threadIdx.x & 31, ty = threadIdx.x >> 5;
    #pragma unroll
    for (int i = ty; i < 32; i += 8) t[i][tx] = f2bf(in[(long)(k0 + i) * 512 + n0 + tx]);
    __syncthreads();
    #pragma unroll
    for (int i = ty; i < 32; i += 8) out[(long)(n0 + i) * 512 + k0 + tx] = t[tx][i];
}

// generic transpose (for W1/W2): out[z*outLS + n*K + k] = bf16(in[z*K*N + k*N + n])
__global__ __launch_bounds__(256) void transpose_w(const float* __restrict__ in, u16* __restrict__ out,
                                                   int K, int N, long outLS)
{
    __shared__ u16 t[32][33];
    long bi = (long)blockIdx.z * K * N, bo = (long)blockIdx.z * outLS;
    int k0 = blockIdx.y * 32, n0 = blockIdx.x * 32;
    int tx = threadIdx.x & 31, ty = threadIdx.x >> 5;
    #pragma unroll
    for (int i = ty; i < 32; i += 8) t[i][tx] = f2bf(in[bi + (long)(k0 + i) * N + n0 + tx]);
    __syncthreads();
    #pragma unroll
    for (int i = ty; i < 32; i += 8) out[bo + (long)(n0 + i) * K + k0 + tx] = t[tx][i];
}

// concat per-layer bias vectors (each NLAY x 512) into [NLAY][nsrc*512]
__global__ __launch_bounds__(256) void concat_bias(const float* __restrict__ a, const float* __restrict__ b,
                                                   const float* __restrict__ c, float* __restrict__ out, int nsrc)
{
    int i = blockIdx.x * 256 + threadIdx.x;
    int col = i & 511, j = (i >> 9) % nsrc, l = i / (nsrc * 512);
    const float* s = (j == 0) ? a : (j == 1) ? b : c;
    out[i] = s[l * 512 + col];
}

__global__ __launch_bounds__(256) void conv_f32_bf16(const float* __restrict__ in, u16* __restrict__ out)
{
    long i = ((long)blockIdx.x * 256 + threadIdx.x) * 4;
    float4 v = *(const float4*)(in + i);
    u16x4 o; o.x = f2bf(v.x); o.y = f2bf(v.y); o.z = f2bf(v.z); o.w = f2bf(v.w);
    *(u16x4*)(out + i) = o;
}

// ---------------------------------------------------------------------------
// Embedding * sqrt(D) + sinusoidal positional encoding -> x (f32) and xb (bf16)
// ---------------------------------------------------------------------------
__global__ __launch_bounds__(256) void embed_pe(const int* __restrict__ targets, const float* __restrict__ emb,
                                                float* __restrict__ x, u16* __restrict__ xb)
{
    int t4 = (blockIdx.x * 256 + threadIdx.x) * 4;
    int d = t4 & (DIM - 1);
    int s = (t4 >> 9) & (SEQ - 1);
    int b = t4 >> 18;
    int tok = targets[s * BATCH + b];
    float4 e = *(const float4*)(emb + (long)tok * DIM + d);
    float o[4]; u16x4 ob;
    const float ef[4] = { e.x, e.y, e.z, e.w };
    #pragma unroll
    for (int j = 0; j < 4; ++j) {
        int dd = d + j;
        float div = expf((float)(dd & ~1) * -0.017988946039016f);  // -ln(10000)/512
        float ang = (float)s * div;
        float pe = (dd & 1) ? cosf(ang) : sinf(ang);
        float val = ef[j] * 22.627416997969522f + pe;              // sqrt(512)
        o[j] = val; ob[j] = f2bf(val);
    }
    long idx = ((long)b * SEQ + s) * DIM + d;
    *(float4*)(x + idx) = *(const float4*)o;
    *(u16x4*)(xb + idx) = ob;
}

// scatter helpers: (B*S, D)-indexed value -> head-split layouts
DEV void scat_sd(u16* dst, int mm, int col, float v) {   // (B,NH,S,DH)
    dst[(long)((mm >> 9) * NHEAD + (col >> 6)) * HD + (long)(mm & 511) * DHEAD + (col & 63)] = f2bf(v);
}
DEV void scat_ds(u16* dst, int mm, int col, float v) {   // (B,NH,DH,S)
    dst[(long)((mm >> 9) * NHEAD + (col >> 6)) * HD + (long)(col & 63) * SEQ + (mm & 511)] = f2bf(v);
}

// ---------------------------------------------------------------------------
// GEMM: C = A @ Bt^T + bias.  BM x BN tile, BK=64, 4 waves (wave BM/2 x BN/2).
// global_load_lds width-16 into linear LDS, double-buffered, one barrier per
// K-step. Both-sides XOR swizzle (stage source col pre-permuted, read byte
// XOR (fr&7)<<4) keeps ds_read_b128 conflict-free at 128B row stride.
// A pointer per block: n0 < aSplit ? A0 : A1 (fused cross Q|K|V).
// 1D grid + bijective XCD-chunk swizzle (grid % 8 == 0).
// EPI: 0=bf16 plain, 1=bf16+relu, 4=QKV head-split scatter
// ---------------------------------------------------------------------------
template <int BM, int BN, int EPI>
__global__ __launch_bounds__(256) void gemm_t(const u16* __restrict__ A0, const u16* __restrict__ A1,
                                              const u16* __restrict__ Bt,
                                              void* __restrict__ C0, void* __restrict__ C1, void* __restrict__ C2,
                                              const float* __restrict__ bias, int K, int ldc, int gx, int aSplit)
{
    constexpr int NCHA = BM / 8;          // 8-row A chunks
    constexpr int NCH  = (BM + BN) / 8;   // total chunks per buffer
    constexpr int MI   = BM / 32;         // M frags per wave
    constexpr int NI   = BN / 32;         // N frags per wave
    __shared__ __align__(16) u16 lds[2][NCH * 512];

    const int tid = threadIdx.x, lane = tid & 63, wid = tid >> 6;
    const int nwg = gridDim.x, bid = blockIdx.x;
    const int wg = (bid & 7) * (nwg >> 3) + (bid >> 3);     // XCD-chunk swizzle
    const int m0 = (wg / gx) * BM, n0 = (wg % gx) * BN;
    const u16* A = (n0 < aSplit) ? A0 : A1;
    const int wr = (wid >> 1) * (BM / 2), wc = (wid & 1) * (BN / 2);
    const int fr = lane & 15, fq = lane >> 4;
    const int srow = lane >> 3;                              // 0..7 row in chunk
    const int scol = ((lane & 7) ^ srow) * 8;                // pre-swizzled source col

    f32x4 acc[MI][NI] = {};

    auto stage = [&](int buf, int k0) {
        #pragma unroll
        for (int c = wid; c < NCH; c += 4) {
            if (c < NCHA) gl_lds16(A  + (long)(m0 + c * 8 + srow) * K + k0 + scol, &lds[buf][c * 512]);
            else          gl_lds16(Bt + (long)(n0 + (c - NCHA) * 8 + srow) * K + k0 + scol, &lds[buf][c * 512]);
        }
    };

    const int nt = K >> 6;
    stage(0, 0);
    __syncthreads();                        // drains vmcnt(0): buf0 ready
    int cur = 0;
    const int swz = (fr & 7) << 4;
    for (int t = 0; t < nt; ++t) {
        if (t + 1 < nt) stage(cur ^ 1, (t + 1) << 6);
        const char* lb = (const char*)&lds[cur][0];
        bf16x8 a[MI][2], b[NI][2];
        #pragma unroll
        for (int mi = 0; mi < MI; ++mi)
            #pragma unroll
            for (int kk = 0; kk < 2; ++kk)
                a[mi][kk] = *(const bf16x8*)(lb + (wr + mi * 16 + fr) * 128 + ((kk * 64 + fq * 16) ^ swz));
        #pragma unroll
        for (int ni = 0; ni < NI; ++ni)
            #pragma unroll
            for (int kk = 0; kk < 2; ++kk)
                b[ni][kk] = *(const bf16x8*)(lb + (BM + wc + ni * 16 + fr) * 128 + ((kk * 64 + fq * 16) ^ swz));
        #pragma unroll
        for (int kk = 0; kk < 2; ++kk)
            #pragma unroll
            for (int mi = 0; mi < MI; ++mi)
                #pragma unroll
                for (int ni = 0; ni < NI; ++ni)
                    acc[mi][ni] = __builtin_amdgcn_mfma_f32_16x16x32_bf16(a[mi][kk], b[ni][kk], acc[mi][ni], 0, 0, 0);
        __syncthreads();
        cur ^= 1;
    }

    #pragma unroll
    for (int mi = 0; mi < MI; ++mi)
    #pragma unroll
    for (int ni = 0; ni < NI; ++ni)
    #pragma unroll
    for (int rr = 0; rr < 4; ++rr) {
        int mm = m0 + wr + mi * 16 + fq * 4 + rr;
        int nn = n0 + wc + ni * 16 + fr;
        float v = acc[mi][ni][rr] + bias[nn];
        if (EPI == 0) {
            ((u16*)C0)[(long)mm * ldc + nn] = f2bf(v);
        } else if (EPI == 1) {
            ((u16*)C0)[(long)mm * ldc + nn] = f2bf(fmaxf(v, 0.f));
        } else {            // QKV head-split
            int which = nn >> 9, col = nn & 511;
            if (which == 0)      scat_sd((u16*)C0, mm, col, v);
            else if (which == 1) scat_sd((u16*)C1, mm, col, v);
            else                 scat_ds((u16*)C2, mm, col, v);
        }
    }
}

// ---------------------------------------------------------------------------
// Flash attention: block = one (head, 64 q-rows). 4 waves x 16 rows.
// KV tiles of 128, double-buffered LDS, both-sides XOR swizzle on K and V
// (128B/256B row strides are 16-way conflicts unswizzled). Online softmax in
// C-layout registers; P via swizzled per-wave LDS slab. setprio around MFMA.
// ---------------------------------------------------------------------------
template <bool CAUSAL>
__global__ __launch_bounds__(256) void flash_attn(const u16* __restrict__ qh, const u16* __restrict__ kh,
                                                  const u16* __restrict__ vT, u16* __restrict__ ctx)
{
    constexpr int KVB = 128;
    __shared__ __align__(16) u16 Kl[2][KVB * 64];    // kv x dh, swizzled
    __shared__ __align__(16) u16 Vl[2][64 * KVB];    // dh x kv, swizzled
    __shared__ __align__(16) u16 Pl[4][16 * KVB];    // per-wave P, swizzled
    const int lane = threadIdx.x & 63, wid = threadIdx.x >> 6;
    const int head = blockIdx.x >> 3, qt = blockIdx.x & 7;
    const int q0 = qt * 64;
    const long hb = (long)head * HD;
    const int fr = lane & 15, fq = lane >> 4;
    const int swz = (fr & 7) << 4;

    bf16x8 qf[2];
    #pragma unroll
    for (int kf = 0; kf < 2; ++kf)
        qf[kf] = *(const bf16x8*)(qh + hb + (long)(q0 + wid * 16 + fr) * 64 + kf * 32 + fq * 8);

    const int nt = CAUSAL ? (q0 >> 7) + 1 : SEQ / KVB;

    auto stage = [&](int buf, int t) {
        const long kv0 = (long)t * KVB;
        const int kr = lane >> 3;                        // K: 8 rows/chunk
        const int kcol = ((lane & 7) ^ kr) * 8;          // (row&7)==kr
        for (int c = wid; c < 16; c += 4)
            gl_lds16(kh + hb + (kv0 + c * 8 + kr) * 64 + kcol, &Kl[buf][c * 512]);
        const int vr = lane >> 4;                        // V^T: 4 rows/chunk
        for (int c = wid; c < 16; c += 4) {
            int row = c * 4 + vr;
            int vcol = ((lane & 15) ^ (row & 7)) * 8;
            gl_lds16(vT + hb + (long)row * SEQ + kv0 + vcol, &Vl[buf][c * 512]);
        }
    };

    float m[4], l[4];
    #pragma unroll
    for (int r = 0; r < 4; ++r) { m[r] = -3.0e38f; l[r] = 0.f; }
    f32x4 ao[4] = {};

    stage(0, 0);
    __syncthreads();
    int cur = 0;
    for (int t = 0; t < nt; ++t) {
        if (t + 1 < nt) stage(cur ^ 1, t + 1);
        f32x4 as[8] = {};
        const char* kb = (const char*)&Kl[cur][0];
        __builtin_amdgcn_s_setprio(1);
        #pragma unroll
        for (int nf = 0; nf < 8; ++nf)
            #pragma unroll
            for (int kf = 0; kf < 2; ++kf) {
                bf16x8 kfr = *(const bf16x8*)(kb + (nf * 16 + fr) * 128 + ((kf * 64 + fq * 16) ^ swz));
                as[nf] = __builtin_amdgcn_mfma_f32_16x16x32_bf16(qf[kf], kfr, as[nf], 0, 0, 0);
            }
        __builtin_amdgcn_s_setprio(0);
        const int kv0 = t * KVB;
        const int qrow = q0 + wid * 16 + fq * 4;
        #pragma unroll
        for (int nf = 0; nf < 8; ++nf)
            #pragma unroll
            for (int rr = 0; rr < 4; ++rr) {
                float s = as[nf][rr] * 0.125f;
                if (CAUSAL && (kv0 + nf * 16 + fr > qrow + rr)) s = -3.0e38f;
                as[nf][rr] = s;
            }
        float p_scale[4];
        #pragma unroll
        for (int rr = 0; rr < 4; ++rr) {
            float mx = as[0][rr];
            #pragma unroll
            for (int nf = 1; nf < 8; ++nf) mx = fmaxf(mx, as[nf][rr]);
            #pragma unroll
            for (int o = 1; o < 16; o <<= 1) mx = fmaxf(mx, __shfl_xor(mx, o, 64));
            float mnew = fmaxf(m[rr], mx);
            p_scale[rr] = __expf(m[rr] - mnew);
            m[rr] = mnew;
        }
        float rsum[4] = {0.f, 0.f, 0.f, 0.f};
        u16* pw = &Pl[wid][0];
        #pragma unroll
        for (int nf = 0; nf < 8; ++nf)
            #pragma unroll
            for (int rr = 0; rr < 4; ++rr) {
                float p = __expf(as[nf][rr] - m[rr]);
                rsum[rr] += p;
                int row = fq * 4 + rr;
                int byte = (row * 256 + (nf * 16 + fr) * 2) ^ ((row & 7) << 4);
                *(u16*)((char*)pw + byte) = f2bf(p);
            }
        #pragma unroll
        for (int rr = 0; rr < 4; ++rr) {
            #pragma unroll
            for (int o = 1; o < 16; o <<= 1) rsum[rr] += __shfl_xor(rsum[rr], o, 64);
            l[rr] = l[rr] * p_scale[rr] + rsum[rr];
        }
        #pragma unroll
        for (int nf = 0; nf < 4; ++nf)
            #pragma unroll
            for (int rr = 0; rr < 4; ++rr) ao[nf][rr] *= p_scale[rr];
        const char* vb = (const char*)&Vl[cur][0];
        __builtin_amdgcn_s_setprio(1);
        #pragma unroll
        for (int kf = 0; kf < 4; ++kf) {
            int pbyte = (fr * 256 + kf * 64 + fq * 16) ^ swz;
            bf16x8 pa = *(const bf16x8*)((const char*)pw + pbyte);
            #pragma unroll
            for (int nf = 0; nf < 4; ++nf) {
                bf16x8 vf = *(const bf16x8*)(vb + (nf * 16 + fr) * 256 + ((kf * 64 + fq * 16) ^ swz));
                ao[nf] = __builtin_amdgcn_mfma_f32_16x16x32_bf16(pa, vf, ao[nf], 0, 0, 0);
            }
        }
        __builtin_amdgcn_s_setprio(0);
        __syncthreads();
        cur ^= 1;
    }
    const int b = head >> 3, h = head & 7;
    #pragma unroll
    for (int nf = 0; nf < 4; ++nf)
        #pragma unroll
        for (int rr = 0; rr < 4; ++rr) {
            int qq = q0 + wid * 16 + fq * 4 + rr;
            ctx[((long)(b * SEQ + qq)) * DIM + h * 64 + nf * 16 + fr] = f2bf(ao[nf][rr] / l[rr]);
        }
}

// ---------------------------------------------------------------------------
// x = LayerNorm(x + y) * g + be;  y is bf16. Writes f32 (xo) and bf16 (xb).
// ---------------------------------------------------------------------------
__global__ __launch_bounds__(256) void add_ln(const float* x, const u16* __restrict__ y,
                                              float* xo, u16* __restrict__ xb,
                                              const float* __restrict__ g, const float* __restrict__ be)
{
    int row = blockIdx.x * 4 + (threadIdx.x >> 6);
    int lane = threadIdx.x & 63;
    long off = (long)row * DIM + lane * 8;
    float v[8];
    {
        float4 a0 = *(const float4*)(x + off);
        float4 a1 = *(const float4*)(x + off + 4);
        u16x8 yv = *(const u16x8*)(y + off);
        v[0] = a0.x + bf2f(yv[0]); v[1] = a0.y + bf2f(yv[1]);
        v[2] = a0.z + bf2f(yv[2]); v[3] = a0.w + bf2f(yv[3]);
        v[4] = a1.x + bf2f(yv[4]); v[5] = a1.y + bf2f(yv[5]);
        v[6] = a1.z + bf2f(yv[6]); v[7] = a1.w + bf2f(yv[7]);
    }
    float sum = 0.f;
    #pragma unroll
    for (int j = 0; j < 8; ++j) sum += v[j];
    #pragma unroll
    for (int o = 32; o; o >>= 1) sum += __shfl_xor(sum, o, 64);
    float mean = sum * (1.0f / DIM);
    float vs = 0.f;
    #pragma unroll
    for (int j = 0; j < 8; ++j) { float d = v[j] - mean; vs += d * d; }
    #pragma unroll
    for (int o = 32; o; o >>= 1) vs += __shfl_xor(vs, o, 64);
    float rstd = rsqrtf(vs * (1.0f / DIM) + 1e-5f);
    float outv[8]; u16x8 ob;
    #pragma unroll
    for (int j = 0; j < 8; ++j) {
        int col = lane * 8 + j;
        float r = (v[j] - mean) * rstd * g[col] + be[col];
        outv[j] = r; ob[j] = f2bf(r);
    }
    *(float4*)(xo + off)     = *(const float4*)&outv[0];
    *(float4*)(xo + off + 4) = *(const float4*)&outv[4];
    *(u16x8*)(xb + off) = ob;
}

// ---------------------------------------------------------------------------
extern "C" void kernel_launch(void* const* d_in, const int* in_sizes, int n_in,
                              void* d_out, int out_size, void* d_ws, size_t ws_size,
                              hipStream_t stream)
{
    const int*   targets = (const int*)  d_in[0];
    const float* memory  = (const float*)d_in[1];
    // d_in[2]=trg_mask (causal, analytic), d_in[3]=memory_mask (all false) -> unread
    const float* emb     = (const float*)d_in[4];
    const float* Wg[8]; for (int i = 0; i < 8; ++i) Wg[i] = (const float*)d_in[5 + i];
    const float* bg[8]; for (int i = 0; i < 8; ++i) bg[i] = (const float*)d_in[13 + i];
    const float* W1  = (const float*)d_in[21];
    const float* b1  = (const float*)d_in[22];
    const float* W2  = (const float*)d_in[23];
    const float* b2  = (const float*)d_in[24];
    const float* g1  = (const float*)d_in[25];
    const float* g2  = (const float*)d_in[26];
    const float* g3  = (const float*)d_in[27];
    const float* be1 = (const float*)d_in[28];
    const float* be2 = (const float*)d_in[29];
    const float* be3 = (const float*)d_in[30];

    char* w = (char*)d_ws;
    auto take = [&](size_t n) -> char* { char* p = w; w += (n + 255) & ~(size_t)255; return p; };
    u16*   wqkvT = (u16*)take((size_t)NLAY * 3 * SQ * 2);   // self  [L][1536][512]
    u16*   wcatT = (u16*)take((size_t)NLAY * 3 * SQ * 2);   // cross [L][1536][512]
    u16*   woT   = (u16*)take((size_t)NLAY * SQ * 2);
    u16*   wocT  = (u16*)take((size_t)NLAY * SQ * 2);
    u16*   w1T   = (u16*)take((size_t)NLAY * DIM * DFFN * 2);
    u16*   w2T   = (u16*)take((size_t)NLAY * DIM * DFFN * 2);
    float* bqkv  = (float*)take((size_t)NLAY * 3 * DIM * 4);
    float* bqkvc = (float*)take((size_t)NLAY * 3 * DIM * 4);
    float* x     = (float*)take((size_t)MROWS * DIM * 4);
    u16*   y     = (u16*)  take((size_t)MROWS * DIM * 2);
    u16*   xb    = (u16*)  take((size_t)MROWS * DIM * 2);
    u16*   memb  = (u16*)  take((size_t)MROWS * DIM * 2);
    u16*   qh    = (u16*)  take((size_t)MROWS * DIM * 2);
    u16*   kh    = (u16*)  take((size_t)MROWS * DIM * 2);
    u16*   vT    = (u16*)  take((size_t)MROWS * DIM * 2);
    u16*   ctx   = (u16*)  take((size_t)MROWS * DIM * 2);
    u16*   h1    = (u16*)  take((size_t)MROWS * DFFN * 2);

    TP tp;
    tp.in[0] = Wg[0]; tp.out[0] = wqkvT;          tp.ls[0] = 3 * SQ;
    tp.in[1] = Wg[1]; tp.out[1] = wqkvT + SQ;     tp.ls[1] = 3 * SQ;
    tp.in[2] = Wg[2]; tp.out[2] = wqkvT + 2 * SQ; tp.ls[2] = 3 * SQ;
    tp.in[3] = Wg[3]; tp.out[3] = woT;            tp.ls[3] = SQ;
    tp.in[4] = Wg[4]; tp.out[4] = wcatT;          tp.ls[4] = 3 * SQ;
    tp.in[5] = Wg[5]; tp.out[5] = wcatT + SQ;     tp.ls[5] = 3 * SQ;
    tp.in[6] = Wg[6]; tp.out[6] = wcatT + 2 * SQ; tp.ls[6] = 3 * SQ;
    tp.in[7] = Wg[7]; tp.out[7] = wocT;           tp.ls[7] = SQ;
    transpose8<<<dim3(16, 16, 8 * NLAY), 256, 0, stream>>>(tp);
    transpose_w<<<dim3(64, 16, NLAY), 256, 0, stream>>>(W1, w1T, DIM, DFFN, (long)DIM * DFFN);
    transpose_w<<<dim3(16, 64, NLAY), 256, 0, stream>>>(W2, w2T, DFFN, DIM, (long)DIM * DFFN);
    concat_bias<<<NLAY * 3 * DIM / 256, 256, 0, stream>>>(bg[0], bg[1], bg[2], bqkv, 3);
    concat_bias<<<NLAY * 3 * DIM / 256, 256, 0, stream>>>(bg[4], bg[5], bg[6], bqkvc, 3);
    conv_f32_bf16<<<2048, 256, 0, stream>>>(memory, memb);
    embed_pe<<<2048, 256, 0, stream>>>(targets, emb, x, xb);

    const int BIG = 1 << 30;
    for (int i = 0; i < NLAY; ++i) {
        const u16 *wqkv = wqkvT + (long)i * 3 * SQ, *wcat = wcatT + (long)i * 3 * SQ;
        const u16 *wo = woT + (long)i * SQ, *woc = wocT + (long)i * SQ;
        const u16 *w1t = w1T + (long)i * DIM * DFFN, *w2t = w2T + (long)i * DIM * DFFN;
        const float *bo = bg[3] + i * DIM, *boc = bg[7] + i * DIM;

        // ---- self attention (causal) ----
        gemm_t<128, 128, 4><<<384, 256, 0, stream>>>(xb, xb, wqkv, qh, kh, vT, bqkv + i * 3 * DIM, DIM, 0, 12, BIG);
        flash_attn<true><<<BATCH * NHEAD * (SEQ / 64), 256, 0, stream>>>(qh, kh, vT, ctx);
        gemm_t<64, 64, 0><<<512, 256, 0, stream>>>(ctx, ctx, wo, y, nullptr, nullptr, bo, DIM, DIM, 8, BIG);
        add_ln<<<MROWS / 4, 256, 0, stream>>>(x, y, x, xb, g1 + i * DIM, be1 + i * DIM);

        // ---- cross attention (no mask): fused Q(from xb) | K,V (from memb) ----
        gemm_t<128, 128, 4><<<384, 256, 0, stream>>>(xb, memb, wcat, qh, kh, vT, bqkvc + i * 3 * DIM, DIM, 0, 12, 512);
        flash_attn<false><<<BATCH * NHEAD * (SEQ / 64), 256, 0, stream>>>(qh, kh, vT, ctx);
        gemm_t<64, 64, 0><<<512, 256, 0, stream>>>(ctx, ctx, woc, y, nullptr, nullptr, boc, DIM, DIM, 8, BIG);
        add_ln<<<MROWS / 4, 256, 0, stream>>>(x, y, x, xb, g2 + i * DIM, be2 + i * DIM);

        // ---- FFN ----
        gemm_t<128, 128, 1><<<512, 256, 0, stream>>>(xb, xb, w1t, h1, nullptr, nullptr, b1 + i * DFFN, DIM, DFFN, 16, BIG);
        gemm_t<64, 64, 0><<<512, 256, 0, stream>>>(h1, h1, w2t, y, nullptr, nullptr, b2 + i * DIM, DFFN, DIM, 8, BIG);
        float* xo = (i == NLAY - 1) ? (float*)d_out : x;
        add_ln<<<MROWS / 4, 256, 0, stream>>>(x, y, xo, xb, g3 + i * DIM, be3 + i * DIM);
    }
}

// Round 7
// 825.953 us; speedup vs baseline: 1.9729x; 1.1199x over previous
//
#include <hip/hip_runtime.h>

typedef unsigned short u16;
typedef unsigned int   u32;
typedef __attribute__((ext_vector_type(4))) u16   u16x4;
typedef __attribute__((ext_vector_type(8))) u16   u16x8;
typedef __attribute__((ext_vector_type(8))) __bf16 bf16x8;
typedef __attribute__((ext_vector_type(4))) float f32x4;

#define DEV static __device__ __forceinline__

constexpr int DIM = 512, NHEAD = 8, DHEAD = 64, DFFN = 2048, NLAY = 6, SEQ = 512, BATCH = 8;
constexpr int MROWS = BATCH * SEQ;            // 4096 token rows
constexpr long HD = (long)SEQ * DHEAD;        // 32768 per-head q/k/v block
constexpr long SQ = (long)DIM * DIM;          // 262144

DEV float bf2f(u16 u) { union { u32 i; float f; } x; x.i = (u32)u << 16; return x.f; }
DEV u16 f2bf(float f) { union { float f; u32 i; } x; x.f = f; u32 r = x.i + 0x7fffu + ((x.i >> 16) & 1u); return (u16)(r >> 16); }

DEV void gl_lds16(const u16* g, u16* l) {
    __builtin_amdgcn_global_load_lds((const __attribute__((address_space(1))) u32*)(const void*)g,
                                     (__attribute__((address_space(3))) u32*)(void*)l, 16, 0, 0);
}

// ---------------------------------------------------------------------------
// Merged transpose for the 8 square (512x512 per layer) weights.
// ---------------------------------------------------------------------------
struct TP { const float* in[8]; u16* out[8]; long ls[8]; };

__global__ __launch_bounds__(256) void transpose8(TP p)
{
    __shared__ u16 t[32][33];
    int z = blockIdx.z, which = z / NLAY, l = z % NLAY;
    const float* in = p.in[which] + (long)l * SQ;
    u16* out = p.out[which] + (long)l * p.ls[which];
    int k0 = blockIdx.y * 32, n0 = blockIdx.x * 32;
    int tx = threadIdx.x & 31, ty = threadIdx.x >> 5;
    #pragma unroll
    for (int i = ty; i < 32; i += 8) t[i][tx] = f2bf(in[(long)(k0 + i) * 512 + n0 + tx]);
    __syncthreads();
    #pragma unroll
    for (int i = ty; i < 32; i += 8) out[(long)(n0 + i) * 512 + k0 + tx] = t[tx][i];
}

// generic transpose (for W1/W2): out[z*outLS + n*K + k] = bf16(in[z*K*N + k*N + n])
__global__ __launch_bounds__(256) void transpose_w(const float* __restrict__ in, u16* __restrict__ out,
                                                   int K, int N, long outLS)
{
    __shared__ u16 t[32][33];
    long bi = (long)blockIdx.z * K * N, bo = (long)blockIdx.z * outLS;
    int k0 = blockIdx.y * 32, n0 = blockIdx.x * 32;
    int tx = threadIdx.x & 31, ty = threadIdx.x >> 5;
    #pragma unroll
    for (int i = ty; i < 32; i += 8) t[i][tx] = f2bf(in[bi + (long)(k0 + i) * N + n0 + tx]);
    __syncthreads();
    #pragma unroll
    for (int i = ty; i < 32; i += 8) out[bo + (long)(n0 + i) * K + k0 + tx] = t[tx][i];
}

// concat per-layer bias vectors (each NLAY x 512) into [NLAY][nsrc*512]
__global__ __launch_bounds__(256) void concat_bias(const float* __restrict__ a, const float* __restrict__ b,
                                                   const float* __restrict__ c, float* __restrict__ out, int nsrc)
{
    int i = blockIdx.x * 256 + threadIdx.x;
    int col = i & 511, j = (i >> 9) % nsrc, l = i / (nsrc * 512);
    const float* s = (j == 0) ? a : (j == 1) ? b : c;
    out[i] = s[l * 512 + col];
}

__global__ __launch_bounds__(256) void conv_f32_bf16(const float* __restrict__ in, u16* __restrict__ out)
{
    long i = ((long)blockIdx.x * 256 + threadIdx.x) * 4;
    float4 v = *(const float4*)(in + i);
    u16x4 o; o.x = f2bf(v.x); o.y = f2bf(v.y); o.z = f2bf(v.z); o.w = f2bf(v.w);
    *(u16x4*)(out + i) = o;
}

// ---------------------------------------------------------------------------
// Embedding * sqrt(D) + sinusoidal positional encoding -> xb (bf16 residual)
// ---------------------------------------------------------------------------
__global__ __launch_bounds__(256) void embed_pe(const int* __restrict__ targets, const float* __restrict__ emb,
                                                u16* __restrict__ xb)
{
    int t4 = (blockIdx.x * 256 + threadIdx.x) * 4;
    int d = t4 & (DIM - 1);
    int s = (t4 >> 9) & (SEQ - 1);
    int b = t4 >> 18;
    int tok = targets[s * BATCH + b];
    float4 e = *(const float4*)(emb + (long)tok * DIM + d);
    u16x4 ob;
    const float ef[4] = { e.x, e.y, e.z, e.w };
    #pragma unroll
    for (int j = 0; j < 4; ++j) {
        int dd = d + j;
        float div = expf((float)(dd & ~1) * -0.017988946039016f);  // -ln(10000)/512
        float ang = (float)s * div;
        float pe = (dd & 1) ? cosf(ang) : sinf(ang);
        ob[j] = f2bf(ef[j] * 22.627416997969522f + pe);            // sqrt(512)
    }
    *(u16x4*)(xb + ((long)b * SEQ + s) * DIM + d) = ob;
}

// scatter helpers: (B*S, D)-indexed value -> head-split layouts
DEV void scat_sd(u16* dst, int mm, int col, float v) {   // (B,NH,S,DH)
    dst[(long)((mm >> 9) * NHEAD + (col >> 6)) * HD + (long)(mm & 511) * DHEAD + (col & 63)] = f2bf(v);
}
DEV void scat_ds(u16* dst, int mm, int col, float v) {   // (B,NH,DH,S)
    dst[(long)((mm >> 9) * NHEAD + (col >> 6)) * HD + (long)(col & 63) * SEQ + (mm & 511)] = f2bf(v);
}

// ---------------------------------------------------------------------------
// GEMM: C = A @ Bt^T + bias.  BM x BN tile, BK=64, 4 waves (wave BM/2 x BN/2).
// global_load_lds width-16 into linear LDS, double-buffered, one barrier per
// K-step. Both-sides XOR swizzle keeps ds_read_b128 conflict-free.
// A pointer per block: n0 < aSplit ? A0 : A1 (fused cross Q|K|V).
// 1D grid + bijective XCD-chunk swizzle (grid % 8 == 0).
// EPI: 0=bf16 plain, 1=bf16+relu, 4=QKV head-split scatter
// ---------------------------------------------------------------------------
template <int BM, int BN, int EPI>
__global__ __launch_bounds__(256) void gemm_t(const u16* __restrict__ A0, const u16* __restrict__ A1,
                                              const u16* __restrict__ Bt,
                                              void* __restrict__ C0, void* __restrict__ C1, void* __restrict__ C2,
                                              const float* __restrict__ bias, int K, int ldc, int gx, int aSplit)
{
    constexpr int NCHA = BM / 8;          // 8-row A chunks
    constexpr int NCH  = (BM + BN) / 8;   // total chunks per buffer
    constexpr int MI   = BM / 32;         // M frags per wave
    constexpr int NI   = BN / 32;         // N frags per wave
    __shared__ __align__(16) u16 lds[2][NCH * 512];

    const int tid = threadIdx.x, lane = tid & 63, wid = tid >> 6;
    const int nwg = gridDim.x, bid = blockIdx.x;
    const int wg = (bid & 7) * (nwg >> 3) + (bid >> 3);     // XCD-chunk swizzle
    const int m0 = (wg / gx) * BM, n0 = (wg % gx) * BN;
    const u16* A = (n0 < aSplit) ? A0 : A1;
    const int wr = (wid >> 1) * (BM / 2), wc = (wid & 1) * (BN / 2);
    const int fr = lane & 15, fq = lane >> 4;
    const int srow = lane >> 3;                              // 0..7 row in chunk
    const int scol = ((lane & 7) ^ srow) * 8;                // pre-swizzled source col

    f32x4 acc[MI][NI] = {};

    auto stage = [&](int buf, int k0) {
        #pragma unroll
        for (int c = wid; c < NCH; c += 4) {
            if (c < NCHA) gl_lds16(A  + (long)(m0 + c * 8 + srow) * K + k0 + scol, &lds[buf][c * 512]);
            else          gl_lds16(Bt + (long)(n0 + (c - NCHA) * 8 + srow) * K + k0 + scol, &lds[buf][c * 512]);
        }
    };

    const int nt = K >> 6;
    stage(0, 0);
    __syncthreads();                        // drains vmcnt(0): buf0 ready
    int cur = 0;
    const int swz = (fr & 7) << 4;
    for (int t = 0; t < nt; ++t) {
        if (t + 1 < nt) stage(cur ^ 1, (t + 1) << 6);
        const char* lb = (const char*)&lds[cur][0];
        bf16x8 a[MI][2], b[NI][2];
        #pragma unroll
        for (int mi = 0; mi < MI; ++mi)
            #pragma unroll
            for (int kk = 0; kk < 2; ++kk)
                a[mi][kk] = *(const bf16x8*)(lb + (wr + mi * 16 + fr) * 128 + ((kk * 64 + fq * 16) ^ swz));
        #pragma unroll
        for (int ni = 0; ni < NI; ++ni)
            #pragma unroll
            for (int kk = 0; kk < 2; ++kk)
                b[ni][kk] = *(const bf16x8*)(lb + (BM + wc + ni * 16 + fr) * 128 + ((kk * 64 + fq * 16) ^ swz));
        #pragma unroll
        for (int kk = 0; kk < 2; ++kk)
            #pragma unroll
            for (int mi = 0; mi < MI; ++mi)
                #pragma unroll
                for (int ni = 0; ni < NI; ++ni)
                    acc[mi][ni] = __builtin_amdgcn_mfma_f32_16x16x32_bf16(a[mi][kk], b[ni][kk], acc[mi][ni], 0, 0, 0);
        __syncthreads();
        cur ^= 1;
    }

    #pragma unroll
    for (int mi = 0; mi < MI; ++mi)
    #pragma unroll
    for (int ni = 0; ni < NI; ++ni)
    #pragma unroll
    for (int rr = 0; rr < 4; ++rr) {
        int mm = m0 + wr + mi * 16 + fq * 4 + rr;
        int nn = n0 + wc + ni * 16 + fr;
        float v = acc[mi][ni][rr] + bias[nn];
        if (EPI == 0) {
            ((u16*)C0)[(long)mm * ldc + nn] = f2bf(v);
        } else if (EPI == 1) {
            ((u16*)C0)[(long)mm * ldc + nn] = f2bf(fmaxf(v, 0.f));
        } else {            // QKV head-split
            int which = nn >> 9, col = nn & 511;
            if (which == 0)      scat_sd((u16*)C0, mm, col, v);
            else if (which == 1) scat_sd((u16*)C1, mm, col, v);
            else                 scat_ds((u16*)C2, mm, col, v);
        }
    }
}

// ---------------------------------------------------------------------------
// Flash attention: block = (head = bid & 63, qt = bid >> 6) so all 8 q-tiles
// of a head land on ONE XCD (consecutive bids round-robin XCDs) -> K/V stays
// in that XCD's L2 (8 heads x 128KB = 1MB << 4MB). 4 waves x 16 q-rows.
// KV tiles of 128, double-buffered LDS, both-sides XOR swizzle on K and V.
// Online softmax in C-layout registers; P via swizzled per-wave LDS slab.
// ---------------------------------------------------------------------------
template <bool CAUSAL>
__global__ __launch_bounds__(256) void flash_attn(const u16* __restrict__ qh, const u16* __restrict__ kh,
                                                  const u16* __restrict__ vT, u16* __restrict__ ctx)
{
    constexpr int KVB = 128;
    __shared__ __align__(16) u16 Kl[2][KVB * 64];    // kv x dh, swizzled
    __shared__ __align__(16) u16 Vl[2][64 * KVB];    // dh x kv, swizzled
    __shared__ __align__(16) u16 Pl[4][16 * KVB];    // per-wave P, swizzled
    const int lane = threadIdx.x & 63, wid = threadIdx.x >> 6;
    const int head = blockIdx.x & 63, qt = blockIdx.x >> 6;   // head-major: XCD = head%8
    const int q0 = qt * 64;
    const long hb = (long)head * HD;
    const int fr = lane & 15, fq = lane >> 4;
    const int swz = (fr & 7) << 4;

    bf16x8 qf[2];
    #pragma unroll
    for (int kf = 0; kf < 2; ++kf)
        qf[kf] = *(const bf16x8*)(qh + hb + (long)(q0 + wid * 16 + fr) * 64 + kf * 32 + fq * 8);

    const int nt = CAUSAL ? (q0 >> 7) + 1 : SEQ / KVB;

    auto stage = [&](int buf, int t) {
        const long kv0 = (long)t * KVB;
        const int kr = lane >> 3;                        // K: 8 rows/chunk
        const int kcol = ((lane & 7) ^ kr) * 8;
        for (int c = wid; c < 16; c += 4)
            gl_lds16(kh + hb + (kv0 + c * 8 + kr) * 64 + kcol, &Kl[buf][c * 512]);
        const int vr = lane >> 4;                        // V^T: 4 rows/chunk
        for (int c = wid; c < 16; c += 4) {
            int row = c * 4 + vr;
            int vcol = ((lane & 15) ^ (row & 7)) * 8;
            gl_lds16(vT + hb + (long)row * SEQ + kv0 + vcol, &Vl[buf][c * 512]);
        }
    };

    float m[4], l[4];
    #pragma unroll
    for (int r = 0; r < 4; ++r) { m[r] = -3.0e38f; l[r] = 0.f; }
    f32x4 ao[4] = {};

    stage(0, 0);
    __syncthreads();
    int cur = 0;
    for (int t = 0; t < nt; ++t) {
        if (t + 1 < nt) stage(cur ^ 1, t + 1);
        f32x4 as[8] = {};
        const char* kb = (const char*)&Kl[cur][0];
        __builtin_amdgcn_s_setprio(1);
        #pragma unroll
        for (int nf = 0; nf < 8; ++nf)
            #pragma unroll
            for (int kf = 0; kf < 2; ++kf) {
                bf16x8 kfr = *(const bf16x8*)(kb + (nf * 16 + fr) * 128 + ((kf * 64 + fq * 16) ^ swz));
                as[nf] = __builtin_amdgcn_mfma_f32_16x16x32_bf16(qf[kf], kfr, as[nf], 0, 0, 0);
            }
        __builtin_amdgcn_s_setprio(0);
        const int kv0 = t * KVB;
        const int qrow = q0 + wid * 16 + fq * 4;
        #pragma unroll
        for (int nf = 0; nf < 8; ++nf)
            #pragma unroll
            for (int rr = 0; rr < 4; ++rr) {
                float s = as[nf][rr] * 0.125f;
                if (CAUSAL && (kv0 + nf * 16 + fr > qrow + rr)) s = -3.0e38f;
                as[nf][rr] = s;
            }
        float p_scale[4];
        #pragma unroll
        for (int rr = 0; rr < 4; ++rr) {
            float mx = as[0][rr];
            #pragma unroll
            for (int nf = 1; nf < 8; ++nf) mx = fmaxf(mx, as[nf][rr]);
            #pragma unroll
            for (int o = 1; o < 16; o <<= 1) mx = fmaxf(mx, __shfl_xor(mx, o, 64));
            float mnew = fmaxf(m[rr], mx);
            p_scale[rr] = __expf(m[rr] - mnew);
            m[rr] = mnew;
        }
        float rsum[4] = {0.f, 0.f, 0.f, 0.f};
        u16* pw = &Pl[wid][0];
        #pragma unroll
        for (int nf = 0; nf < 8; ++nf)
            #pragma unroll
            for (int rr = 0; rr < 4; ++rr) {
                float p = __expf(as[nf][rr] - m[rr]);
                rsum[rr] += p;
                int row = fq * 4 + rr;
                int byte = (row * 256 + (nf * 16 + fr) * 2) ^ ((row & 7) << 4);
                *(u16*)((char*)pw + byte) = f2bf(p);
            }
        #pragma unroll
        for (int rr = 0; rr < 4; ++rr) {
            #pragma unroll
            for (int o = 1; o < 16; o <<= 1) rsum[rr] += __shfl_xor(rsum[rr], o, 64);
            l[rr] = l[rr] * p_scale[rr] + rsum[rr];
        }
        #pragma unroll
        for (int nf = 0; nf < 4; ++nf)
            #pragma unroll
            for (int rr = 0; rr < 4; ++rr) ao[nf][rr] *= p_scale[rr];
        const char* vb = (const char*)&Vl[cur][0];
        __builtin_amdgcn_s_setprio(1);
        #pragma unroll
        for (int kf = 0; kf < 4; ++kf) {
            int pbyte = (fr * 256 + kf * 64 + fq * 16) ^ swz;
            bf16x8 pa = *(const bf16x8*)((const char*)pw + pbyte);
            #pragma unroll
            for (int nf = 0; nf < 4; ++nf) {
                bf16x8 vf = *(const bf16x8*)(vb + (nf * 16 + fr) * 256 + ((kf * 64 + fq * 16) ^ swz));
                ao[nf] = __builtin_amdgcn_mfma_f32_16x16x32_bf16(pa, vf, ao[nf], 0, 0, 0);
            }
        }
        __builtin_amdgcn_s_setprio(0);
        __syncthreads();
        cur ^= 1;
    }
    const int b = head >> 3, h = head & 7;
    #pragma unroll
    for (int nf = 0; nf < 4; ++nf)
        #pragma unroll
        for (int rr = 0; rr < 4; ++rr) {
            int qq = q0 + wid * 16 + fq * 4 + rr;
            ctx[((long)(b * SEQ + qq)) * DIM + h * 64 + nf * 16 + fr] = f2bf(ao[nf][rr] / l[rr]);
        }
}

// ---------------------------------------------------------------------------
// xb = LayerNorm(xb + y) * g + be, in place (bf16 residual stream).
// Row fully read before written -> in-place safe. If xf != nullptr, also
// write f32 copy (final layer output).
// ---------------------------------------------------------------------------
__global__ __launch_bounds__(256) void add_ln(u16* xb, const u16* __restrict__ y,
                                              const float* __restrict__ g, const float* __restrict__ be,
                                              float* __restrict__ xf)
{
    int row = blockIdx.x * 4 + (threadIdx.x >> 6);
    int lane = threadIdx.x & 63;
    long off = (long)row * DIM + lane * 8;
    u16x8 xv = *(const u16x8*)(xb + off);
    u16x8 yv = *(const u16x8*)(y + off);
    float v[8];
    #pragma unroll
    for (int j = 0; j < 8; ++j) v[j] = bf2f(xv[j]) + bf2f(yv[j]);
    float sum = 0.f;
    #pragma unroll
    for (int j = 0; j < 8; ++j) sum += v[j];
    #pragma unroll
    for (int o = 32; o; o >>= 1) sum += __shfl_xor(sum, o, 64);
    float mean = sum * (1.0f / DIM);
    float vs = 0.f;
    #pragma unroll
    for (int j = 0; j < 8; ++j) { float d = v[j] - mean; vs += d * d; }
    #pragma unroll
    for (int o = 32; o; o >>= 1) vs += __shfl_xor(vs, o, 64);
    float rstd = rsqrtf(vs * (1.0f / DIM) + 1e-5f);
    float outv[8]; u16x8 ob;
    #pragma unroll
    for (int j = 0; j < 8; ++j) {
        int col = lane * 8 + j;
        float r = (v[j] - mean) * rstd * g[col] + be[col];
        outv[j] = r; ob[j] = f2bf(r);
    }
    *(u16x8*)(xb + off) = ob;
    if (xf) {
        *(float4*)(xf + off)     = *(const float4*)&outv[0];
        *(float4*)(xf + off + 4) = *(const float4*)&outv[4];
    }
}

// ---------------------------------------------------------------------------
extern "C" void kernel_launch(void* const* d_in, const int* in_sizes, int n_in,
                              void* d_out, int out_size, void* d_ws, size_t ws_size,
                              hipStream_t stream)
{
    const int*   targets = (const int*)  d_in[0];
    const float* memory  = (const float*)d_in[1];
    // d_in[2]=trg_mask (causal, analytic), d_in[3]=memory_mask (all false) -> unread
    const float* emb     = (const float*)d_in[4];
    const float* Wg[8]; for (int i = 0; i < 8; ++i) Wg[i] = (const float*)d_in[5 + i];
    const float* bg[8]; for (int i = 0; i < 8; ++i) bg[i] = (const float*)d_in[13 + i];
    const float* W1  = (const float*)d_in[21];
    const float* b1  = (const float*)d_in[22];
    const float* W2  = (const float*)d_in[23];
    const float* b2  = (const float*)d_in[24];
    const float* g1  = (const float*)d_in[25];
    const float* g2  = (const float*)d_in[26];
    const float* g3  = (const float*)d_in[27];
    const float* be1 = (const float*)d_in[28];
    const float* be2 = (const float*)d_in[29];
    const float* be3 = (const float*)d_in[30];

    char* w = (char*)d_ws;
    auto take = [&](size_t n) -> char* { char* p = w; w += (n + 255) & ~(size_t)255; return p; };
    u16*   wqkvT = (u16*)take((size_t)NLAY * 3 * SQ * 2);   // self  [L][1536][512]
    u16*   wcatT = (u16*)take((size_t)NLAY * 3 * SQ * 2);   // cross [L][1536][512]
    u16*   woT   = (u16*)take((size_t)NLAY * SQ * 2);
    u16*   wocT  = (u16*)take((size_t)NLAY * SQ * 2);
    u16*   w1T   = (u16*)take((size_t)NLAY * DIM * DFFN * 2);
    u16*   w2T   = (u16*)take((size_t)NLAY * DIM * DFFN * 2);
    float* bqkv  = (float*)take((size_t)NLAY * 3 * DIM * 4);
    float* bqkvc = (float*)take((size_t)NLAY * 3 * DIM * 4);
    u16*   xb    = (u16*)  take((size_t)MROWS * DIM * 2);   // bf16 residual stream
    u16*   y     = (u16*)  take((size_t)MROWS * DIM * 2);
    u16*   memb  = (u16*)  take((size_t)MROWS * DIM * 2);
    u16*   qh    = (u16*)  take((size_t)MROWS * DIM * 2);
    u16*   kh    = (u16*)  take((size_t)MROWS * DIM * 2);
    u16*   vT    = (u16*)  take((size_t)MROWS * DIM * 2);
    u16*   ctx   = (u16*)  take((size_t)MROWS * DIM * 2);
    u16*   h1    = (u16*)  take((size_t)MROWS * DFFN * 2);

    TP tp;
    tp.in[0] = Wg[0]; tp.out[0] = wqkvT;          tp.ls[0] = 3 * SQ;
    tp.in[1] = Wg[1]; tp.out[1] = wqkvT + SQ;     tp.ls[1] = 3 * SQ;
    tp.in[2] = Wg[2]; tp.out[2] = wqkvT + 2 * SQ; tp.ls[2] = 3 * SQ;
    tp.in[3] = Wg[3]; tp.out[3] = woT;            tp.ls[3] = SQ;
    tp.in[4] = Wg[4]; tp.out[4] = wcatT;          tp.ls[4] = 3 * SQ;
    tp.in[5] = Wg[5]; tp.out[5] = wcatT + SQ;     tp.ls[5] = 3 * SQ;
    tp.in[6] = Wg[6]; tp.out[6] = wcatT + 2 * SQ; tp.ls[6] = 3 * SQ;
    tp.in[7] = Wg[7]; tp.out[7] = wocT;           tp.ls[7] = SQ;
    transpose8<<<dim3(16, 16, 8 * NLAY), 256, 0, stream>>>(tp);
    transpose_w<<<dim3(64, 16, NLAY), 256, 0, stream>>>(W1, w1T, DIM, DFFN, (long)DIM * DFFN);
    transpose_w<<<dim3(16, 64, NLAY), 256, 0, stream>>>(W2, w2T, DFFN, DIM, (long)DIM * DFFN);
    concat_bias<<<NLAY * 3 * DIM / 256, 256, 0, stream>>>(bg[0], bg[1], bg[2], bqkv, 3);
    concat_bias<<<NLAY * 3 * DIM / 256, 256, 0, stream>>>(bg[4], bg[5], bg[6], bqkvc, 3);
    conv_f32_bf16<<<2048, 256, 0, stream>>>(memory, memb);
    embed_pe<<<2048, 256, 0, stream>>>(targets, emb, xb);

    const int BIG = 1 << 30;
    for (int i = 0; i < NLAY; ++i) {
        const u16 *wqkv = wqkvT + (long)i * 3 * SQ, *wcat = wcatT + (long)i * 3 * SQ;
        const u16 *wo = woT + (long)i * SQ, *woc = wocT + (long)i * SQ;
        const u16 *w1t = w1T + (long)i * DIM * DFFN, *w2t = w2T + (long)i * DIM * DFFN;
        const float *bo = bg[3] + i * DIM, *boc = bg[7] + i * DIM;

        // ---- self attention (causal) ----
        gemm_t<128, 128, 4><<<384, 256, 0, stream>>>(xb, xb, wqkv, qh, kh, vT, bqkv + i * 3 * DIM, DIM, 0, 12, BIG);
        flash_attn<true><<<BATCH * NHEAD * (SEQ / 64), 256, 0, stream>>>(qh, kh, vT, ctx);
        gemm_t<64, 64, 0><<<512, 256, 0, stream>>>(ctx, ctx, wo, y, nullptr, nullptr, bo, DIM, DIM, 8, BIG);
        add_ln<<<MROWS / 4, 256, 0, stream>>>(xb, y, g1 + i * DIM, be1 + i * DIM, nullptr);

        // ---- cross attention (no mask): fused Q(from xb) | K,V (from memb) ----
        gemm_t<128, 128, 4><<<384, 256, 0, stream>>>(xb, memb, wcat, qh, kh, vT, bqkvc + i * 3 * DIM, DIM, 0, 12, 512);
        flash_attn<false><<<BATCH * NHEAD * (SEQ / 64), 256, 0, stream>>>(qh, kh, vT, ctx);
        gemm_t<64, 64, 0><<<512, 256, 0, stream>>>(ctx, ctx, woc, y, nullptr, nullptr, boc, DIM, DIM, 8, BIG);
        add_ln<<<MROWS / 4, 256, 0, stream>>>(xb, y, g2 + i * DIM, be2 + i * DIM, nullptr);

        // ---- FFN ----
        gemm_t<128, 128, 1><<<512, 256, 0, stream>>>(xb, xb, w1t, h1, nullptr, nullptr, b1 + i * DFFN, DIM, DFFN, 16, BIG);
        gemm_t<64, 64, 0><<<512, 256, 0, stream>>>(h1, h1, w2t, y, nullptr, nullptr, b2 + i * DIM, DFFN, DIM, 8, BIG);
        add_ln<<<MROWS / 4, 256, 0, stream>>>(xb, y, g3 + i * DIM, be3 + i * DIM,
                                              (i == NLAY - 1) ? (float*)d_out : nullptr);
    }
}